// Round 1
// baseline (1053.295 us; speedup 1.0000x reference)
//
#include <hip/hip_runtime.h>

#define SEQ 4096
#define BATCH 4
#define EMB 512
#define NHEAD 8
#define HDIM 64
#define NCHUNK 1024
#define TOPK 8
#define SCALING 0.125f

// ---------------------------------------------------------------------------
// Chunk-mean pooling of hidden states: Hp[b,c,e] = mean_{j<4} H[b, 4c+j, e]
// (pooling commutes with the linear projections, so pooled_k = Hp @ Wk)
// ---------------------------------------------------------------------------
__global__ __launch_bounds__(256) void pool_kernel(const float* __restrict__ H,
                                                   float* __restrict__ Hp) {
  size_t o = (size_t)blockIdx.x * 256 + threadIdx.x;  // < BATCH*NCHUNK*EMB
  int e = o & 511;
  size_t bc = o >> 9;            // b*NCHUNK + c
  size_t b = bc >> 10, c = bc & 1023;
  const float* p = H + (((b * SEQ) + c * 4) << 9) + e;
  Hp[o] = 0.25f * (p[0] + p[512] + p[1024] + p[1536]);
}

// ---------------------------------------------------------------------------
// Tiled f32 GEMM: C(M,N) = A(M,K) @ B(K,N), row-major, 64x64 tile, BK=16,
// 256 threads, 4x4 microtile per thread. M % 64 == 0, N % 64 == 0, K % 16 == 0.
// ---------------------------------------------------------------------------
__global__ __launch_bounds__(256) void sgemm64(const float* __restrict__ A,
                                               const float* __restrict__ Bm,
                                               float* __restrict__ C,
                                               int M, int N, int K) {
  __shared__ float As[16][68];  // stored transposed: As[k][m]
  __shared__ float Bs[16][68];  // Bs[k][n]
  const int tid = threadIdx.x;
  const int tx = tid & 15, ty = tid >> 4;
  const int row0 = blockIdx.y * 64, col0 = blockIdx.x * 64;
  float acc[4][4] = {};
  const int ar = tid >> 2, ac = (tid & 3) << 2;   // A tile load coords
  const int br = tid >> 4, bc = (tid & 15) << 2;  // B tile load coords
  for (int k0 = 0; k0 < K; k0 += 16) {
    float4 a4 = *(const float4*)&A[(size_t)(row0 + ar) * K + k0 + ac];
    float4 b4 = *(const float4*)&Bm[(size_t)(k0 + br) * N + col0 + bc];
    As[ac + 0][ar] = a4.x;
    As[ac + 1][ar] = a4.y;
    As[ac + 2][ar] = a4.z;
    As[ac + 3][ar] = a4.w;
    *(float4*)&Bs[br][bc] = b4;
    __syncthreads();
#pragma unroll
    for (int k = 0; k < 16; ++k) {
      float4 av = *(const float4*)&As[k][ty * 4];
      float4 bv = *(const float4*)&Bs[k][tx * 4];
      float a[4] = {av.x, av.y, av.z, av.w};
      float b[4] = {bv.x, bv.y, bv.z, bv.w};
#pragma unroll
      for (int i = 0; i < 4; ++i)
#pragma unroll
        for (int j = 0; j < 4; ++j) acc[i][j] += a[i] * b[j];
    }
    __syncthreads();
  }
#pragma unroll
  for (int i = 0; i < 4; ++i) {
    float4 o = make_float4(acc[i][0], acc[i][1], acc[i][2], acc[i][3]);
    *(float4*)&C[(size_t)(row0 + ty * 4 + i) * N + col0 + tx * 4] = o;
  }
}

// ---------------------------------------------------------------------------
// Routing: route[b,c] = max_{h,s} dot(q[b,s,h,:], Pk[b,c,h,:])
// (SCALING > 0 is order-preserving; applied implicitly — only order matters)
// Block = (s-tile of 128, h, b); fused max epilogue; atomicMax on uint keys.
// ---------------------------------------------------------------------------
__device__ __forceinline__ unsigned int float_key(float f) {
  unsigned int bits = __float_as_uint(f);
  return (bits & 0x80000000u) ? ~bits : (bits | 0x80000000u);
}

__global__ __launch_bounds__(256) void route_kernel(const float* __restrict__ Q,
                                                    const float* __restrict__ Pk,
                                                    unsigned int* __restrict__ route) {
  const int b = blockIdx.z, h = blockIdx.y, s0 = blockIdx.x * 128;
  __shared__ float qs[128][64];
  __shared__ float ks[64][65];
  __shared__ float red[4][64];
  const int tid = threadIdx.x;
  const int lane = tid & 63, wv = tid >> 6;
#pragma unroll
  for (int i = 0; i < 8; ++i) {
    int fi = tid + i * 256;
    int r = fi >> 4, c4 = (fi & 15) << 2;
    *(float4*)&qs[r][c4] =
        *(const float4*)&Q[((size_t)(b * SEQ + s0 + r) << 9) + h * HDIM + c4];
  }
  float cmax[16];
#pragma unroll
  for (int i = 0; i < 16; ++i) cmax[i] = -1e30f;
  for (int ct = 0; ct < 16; ++ct) {
    __syncthreads();
#pragma unroll
    for (int i = 0; i < 4; ++i) {
      int fi = tid + i * 256;
      int r = fi >> 4, c4 = (fi & 15) << 2;
      float4 v =
          *(const float4*)&Pk[((size_t)(b * NCHUNK + ct * 64 + r) << 9) + h * HDIM + c4];
      ks[r][c4 + 0] = v.x;
      ks[r][c4 + 1] = v.y;
      ks[r][c4 + 2] = v.z;
      ks[r][c4 + 3] = v.w;
    }
    __syncthreads();
    float kreg[64];
#pragma unroll
    for (int d = 0; d < 64; ++d) kreg[d] = ks[lane][d];
    float m = cmax[ct];
    const int sbase = wv * 32;
#pragma unroll 4
    for (int sl = 0; sl < 32; ++sl) {
      const float* qp = qs[sbase + sl];
      float dot = 0.f;
#pragma unroll
      for (int d4 = 0; d4 < 16; ++d4) {
        float4 q4 = *(const float4*)&qp[d4 * 4];
        dot += q4.x * kreg[d4 * 4] + q4.y * kreg[d4 * 4 + 1] +
               q4.z * kreg[d4 * 4 + 2] + q4.w * kreg[d4 * 4 + 3];
      }
      m = fmaxf(m, dot);
    }
    cmax[ct] = m;
  }
  for (int ct = 0; ct < 16; ++ct) {
    __syncthreads();
    red[wv][lane] = cmax[ct];
    __syncthreads();
    if (tid < 64) {
      float m = fmaxf(fmaxf(red[0][tid], red[1][tid]), fmaxf(red[2][tid], red[3][tid]));
      atomicMax(&route[b * NCHUNK + ct * 64 + tid], float_key(m));
    }
  }
}

// ---------------------------------------------------------------------------
// Top-K per batch (iterative argmax; the selected SET is all that matters —
// softmax over selected chunks is permutation-invariant).
// ---------------------------------------------------------------------------
__global__ __launch_bounds__(256) void topk_kernel(const unsigned int* __restrict__ route,
                                                   int* __restrict__ topidx) {
  const int b = blockIdx.x, tid = threadIdx.x;
  __shared__ unsigned long long keys[NCHUNK];
  __shared__ unsigned long long red[256];
#pragma unroll
  for (int i = 0; i < 4; ++i) {
    int idx = tid + i * 256;
    keys[idx] = ((unsigned long long)route[b * NCHUNK + idx] << 32) |
                (unsigned int)(NCHUNK - 1 - idx);  // tie → lower index wins
  }
  __syncthreads();
  for (int it = 0; it < TOPK; ++it) {
    unsigned long long mx = keys[tid];
#pragma unroll
    for (int i = 1; i < 4; ++i) {
      unsigned long long k = keys[tid + i * 256];
      mx = (k > mx) ? k : mx;
    }
    red[tid] = mx;
    __syncthreads();
    for (int st = 128; st > 0; st >>= 1) {
      if (tid < st) {
        unsigned long long k = red[tid + st];
        if (k > red[tid]) red[tid] = k;
      }
      __syncthreads();
    }
    int widx = NCHUNK - 1 - (int)(red[0] & 0xffffffffu);
    if (tid == 0) {
      topidx[b * TOPK + it] = widx;
      keys[widx] = 0ULL;
    }
    __syncthreads();
  }
}

// ---------------------------------------------------------------------------
// Sparse attention over the 8 selected pooled chunks. One wave per (b,s,h);
// lane = d. Shuffle-reduce for the 8 scores, stable softmax, weighted V sum.
// ---------------------------------------------------------------------------
__global__ __launch_bounds__(256) void attn_kernel(const float* __restrict__ Q,
                                                   const float* __restrict__ Pk,
                                                   const float* __restrict__ Pv,
                                                   const int* __restrict__ topidx,
                                                   float* __restrict__ AO) {
  const int gw = (int)((blockIdx.x * 256 + threadIdx.x) >> 6);  // global wave id
  const int lane = threadIdx.x & 63;
  const int h = gw & 7;
  const int s = (gw >> 3) & (SEQ - 1);
  const int b = gw >> 15;  // / (8*4096)
  const size_t qoff = ((size_t)(b * SEQ + s) << 9) + h * HDIM + lane;
  const float q = Q[qoff];
  float sc[TOPK];
  int cidx[TOPK];
  float m = -1e30f;
#pragma unroll
  for (int j = 0; j < TOPK; ++j) {
    cidx[j] = topidx[b * TOPK + j];
    float kd = Pk[((size_t)(b * NCHUNK + cidx[j]) << 9) + h * HDIM + lane];
    float p = q * kd;
#pragma unroll
    for (int o = 32; o > 0; o >>= 1) p += __shfl_xor(p, o, 64);
    sc[j] = p * SCALING;
    m = fmaxf(m, sc[j]);
  }
  float se = 0.f, w[TOPK];
#pragma unroll
  for (int j = 0; j < TOPK; ++j) {
    w[j] = __expf(sc[j] - m);
    se += w[j];
  }
  const float inv = 1.f / se;
  float o = 0.f;
#pragma unroll
  for (int j = 0; j < TOPK; ++j) {
    o += w[j] * Pv[((size_t)(b * NCHUNK + cidx[j]) << 9) + h * HDIM + lane];
  }
  AO[qoff] = o * inv;
}

// ---------------------------------------------------------------------------
extern "C" void kernel_launch(void* const* d_in, const int* in_sizes, int n_in,
                              void* d_out, int out_size, void* d_ws, size_t ws_size,
                              hipStream_t stream) {
  const float* H  = (const float*)d_in[0];
  const float* Wq = (const float*)d_in[1];
  const float* Wk = (const float*)d_in[2];
  const float* Wv = (const float*)d_in[3];
  const float* Wo = (const float*)d_in[4];
  float* out = (float*)d_out;

  float* ws = (float*)d_ws;
  float* Hp = ws;                               // 4096*512      = 2,097,152
  float* Qb = Hp + 2097152;                     // 16384*512     = 8,388,608
  float* Pk = Qb + 8388608;                     // 4096*512      = 2,097,152
  float* Pv = Pk + 2097152;                     // 4096*512      = 2,097,152
  float* AO = Pv + 2097152;                     // 16384*512     = 8,388,608
  unsigned int* route = (unsigned int*)(AO + 8388608);  // 4096
  int* topidx = (int*)(route + 4096);                    // 32

  // 1. pooled hidden states (pooling commutes with K/V projections)
  pool_kernel<<<8192, 256, 0, stream>>>(H, Hp);
  // 2. Q projection (full seq), pooled K/V projections (1/4 seq)
  sgemm64<<<dim3(8, 256), 256, 0, stream>>>(H, Wq, Qb, BATCH * SEQ, EMB, EMB);
  sgemm64<<<dim3(8, 64), 256, 0, stream>>>(Hp, Wk, Pk, BATCH * NCHUNK, EMB, EMB);
  sgemm64<<<dim3(8, 64), 256, 0, stream>>>(Hp, Wv, Pv, BATCH * NCHUNK, EMB, EMB);
  // 3. routing scores with fused (h,s)-max epilogue
  hipMemsetAsync(route, 0, NCHUNK * BATCH * sizeof(unsigned int), stream);
  route_kernel<<<dim3(32, 8, 4), 256, 0, stream>>>(Qb, Pk, route);
  // 4. top-8 chunk selection per batch
  topk_kernel<<<BATCH, 256, 0, stream>>>(route, topidx);
  // 5. sparse attention over selected chunks
  attn_kernel<<<32768, 256, 0, stream>>>(Qb, Pk, Pv, topidx, AO);
  // 6. output projection
  sgemm64<<<dim3(8, 256), 256, 0, stream>>>(AO, Wo, out, BATCH * SEQ, EMB, EMB);
}

// Round 2
// 297.410 us; speedup vs baseline: 3.5416x; 3.5416x over previous
//
#include <hip/hip_runtime.h>

#define SEQ 4096
#define BATCH 4
#define EMB 512
#define NHEAD 8
#define HDIM 64
#define NCHUNK 1024
#define TOPK 8
#define SCALING 0.125f

typedef unsigned int uint;
typedef unsigned short ushort_t;
typedef __attribute__((ext_vector_type(8))) short short8;
typedef __attribute__((ext_vector_type(4))) float f32x4;
typedef __attribute__((ext_vector_type(4))) unsigned short us4;

// ---- bf16 split helpers (x ~= hi + lo, each bf16; RNE rounding) -----------
__device__ __forceinline__ ushort_t bf16_rn(float x) {
  uint b = __float_as_uint(x);
  return (ushort_t)((b + 0x7FFFu + ((b >> 16) & 1u)) >> 16);
}
__device__ __forceinline__ float bf16_f(ushort_t u) {
  return __uint_as_float(((uint)u) << 16);
}

// ---- async global->LDS, 16B per lane --------------------------------------
__device__ __forceinline__ void load_lds16(const void* g, void* l) {
  __builtin_amdgcn_global_load_lds(
      (const __attribute__((address_space(1))) unsigned int*)g,
      (__attribute__((address_space(3))) unsigned int*)l, 16, 0, 0);
}

__device__ __forceinline__ f32x4 mfma16(short8 a, short8 b, f32x4 c) {
  return __builtin_amdgcn_mfma_f32_16x16x32_bf16(a, b, c, 0, 0, 0);
}

// ---------------------------------------------------------------------------
// Weight prep: Wt[n][k] = W[k][n], split into hi/lo bf16. z selects matrix.
// ---------------------------------------------------------------------------
__global__ __launch_bounds__(256) void wtrans_kernel(
    const float* __restrict__ Wq, const float* __restrict__ Wk,
    const float* __restrict__ Wv, const float* __restrict__ Wo,
    ushort_t* __restrict__ Wtq_h, ushort_t* __restrict__ Wtq_l,
    ushort_t* __restrict__ Wtkv_h, ushort_t* __restrict__ Wtkv_l,
    ushort_t* __restrict__ Wto_h, ushort_t* __restrict__ Wto_l) {
  __shared__ float t[64][65];
  const int z = blockIdx.z;
  const float* src = (z == 0) ? Wq : (z == 1) ? Wk : (z == 2) ? Wv : Wo;
  ushort_t* dh = (z == 0) ? Wtq_h : (z == 3) ? Wto_h : Wtkv_h;
  ushort_t* dl = (z == 0) ? Wtq_l : (z == 3) ? Wto_l : Wtkv_l;
  const size_t obase = (z == 2) ? (size_t)512 * 512 : 0;  // Wv rows 512..1023
  const int k0 = blockIdx.x * 64, n0 = blockIdx.y * 64;
  const int tid = threadIdx.x;
#pragma unroll
  for (int i = 0; i < 4; ++i) {
    int row = (tid >> 4) + i * 16, col = (tid & 15) * 4;
    float4 v = *(const float4*)&src[(size_t)(k0 + row) * 512 + n0 + col];
    t[row][col + 0] = v.x; t[row][col + 1] = v.y;
    t[row][col + 2] = v.z; t[row][col + 3] = v.w;
  }
  __syncthreads();
#pragma unroll
  for (int i = 0; i < 4; ++i) {
    int nrow = (tid >> 4) + i * 16, kcol = (tid & 15) * 4;
    us4 h, l;
#pragma unroll
    for (int j = 0; j < 4; ++j) {
      float v = t[kcol + j][nrow];
      ushort_t hb = bf16_rn(v);
      h[j] = hb;
      l[j] = bf16_rn(v - bf16_f(hb));
    }
    size_t o = obase + (size_t)(n0 + nrow) * 512 + k0 + kcol;
    *(us4*)&dh[o] = h;
    *(us4*)&dl[o] = l;
  }
}

// ---------------------------------------------------------------------------
// Pool + split: H (f32) -> Hh/Hl (bf16 split) and chunk-mean -> Hph/Hpl.
// ---------------------------------------------------------------------------
__global__ __launch_bounds__(256) void pool_split_kernel(
    const float* __restrict__ H, ushort_t* __restrict__ Hh,
    ushort_t* __restrict__ Hl, ushort_t* __restrict__ Hph,
    ushort_t* __restrict__ Hpl) {
  const int idx = blockIdx.x * 256 + threadIdx.x;  // < 4*1024*128
  const int e4 = (idx & 127) << 2;
  const int c = (idx >> 7) & 1023;
  const int b = idx >> 17;
  const size_t rbase = ((size_t)(b * SEQ + c * 4)) * 512 + e4;
  float4 s = make_float4(0.f, 0.f, 0.f, 0.f);
#pragma unroll
  for (int j = 0; j < 4; ++j) {
    float4 v = *(const float4*)&H[rbase + (size_t)j * 512];
    s.x += v.x; s.y += v.y; s.z += v.z; s.w += v.w;
    us4 h, l;
    float a[4] = {v.x, v.y, v.z, v.w};
#pragma unroll
    for (int q = 0; q < 4; ++q) {
      ushort_t hb = bf16_rn(a[q]);
      h[q] = hb;
      l[q] = bf16_rn(a[q] - bf16_f(hb));
    }
    *(us4*)&Hh[rbase + (size_t)j * 512] = h;
    *(us4*)&Hl[rbase + (size_t)j * 512] = l;
  }
  float a[4] = {s.x * 0.25f, s.y * 0.25f, s.z * 0.25f, s.w * 0.25f};
  us4 h, l;
#pragma unroll
  for (int q = 0; q < 4; ++q) {
    ushort_t hb = bf16_rn(a[q]);
    h[q] = hb;
    l[q] = bf16_rn(a[q] - bf16_f(hb));
  }
  size_t po = ((size_t)(b * NCHUNK + c)) * 512 + e4;
  *(us4*)&Hph[po] = h;
  *(us4*)&Hpl[po] = l;
}

// ---------------------------------------------------------------------------
// MFMA GEMM: C(M,512..1024) = A(M,512) @ Bt(N,512)^T, bf16 inputs, f32 acc.
// NPROD==3: split product AhBh + AhBl + AlBh (f32-grade precision).
// Tile 128x128, BK=32, 4 waves (2x2), global_load_lds(16B), swizzled LDS
// (byte ^= ((row>>1)&3)<<4 within 64B rows -> 2-way conflicts only).
// ---------------------------------------------------------------------------
template <int NPROD, bool WH, bool WL, bool WF>
__global__ __launch_bounds__(256) void gemm_mfma(
    const ushort_t* __restrict__ Ah, const ushort_t* __restrict__ Al,
    const ushort_t* __restrict__ Bh, const ushort_t* __restrict__ Bl,
    ushort_t* __restrict__ Ch, ushort_t* __restrict__ Cl,
    float* __restrict__ Cf, int ldc) {
  __shared__ ushort_t lds[2][4][4096];  // [buf][Ah,Bh,Al,Bl][128*32]
  const int tid = threadIdx.x, lane = tid & 63, wv = tid >> 6;
  const int l15 = lane & 15, g = lane >> 4;
  const int wm = wv >> 1, wn = wv & 1;
  const int row0 = blockIdx.y * 128, col0 = blockIdx.x * 128;
  const ushort_t* A0 = Ah + (size_t)row0 * 512;
  const ushort_t* B0 = Bh + (size_t)col0 * 512;
  const ushort_t* A1 = (NPROD == 3) ? Al + (size_t)row0 * 512 : nullptr;
  const ushort_t* B1 = (NPROD == 3) ? Bl + (size_t)col0 * 512 : nullptr;
  f32x4 acc[4][4];
#pragma unroll
  for (int m = 0; m < 4; ++m)
#pragma unroll
    for (int n = 0; n < 4; ++n) acc[m][n] = (f32x4){0.f, 0.f, 0.f, 0.f};

  auto stage = [&](int buf, int t) {
#pragma unroll
    for (int j = 0; j < 2; ++j) {
      int si = j * 256 + wv * 64 + lane;
      int row = si >> 2;
      int kb = ((si & 3) << 4) ^ (((row >> 1) & 3) << 4);
      size_t goff = (size_t)row * 512 + t * 32 + (kb >> 1);
      int doff = (j * 256 + wv * 64) * 8;
      load_lds16(A0 + goff, &lds[buf][0][doff]);
      load_lds16(B0 + goff, &lds[buf][1][doff]);
      if constexpr (NPROD == 3) {
        load_lds16(A1 + goff, &lds[buf][2][doff]);
        load_lds16(B1 + goff, &lds[buf][3][doff]);
      }
    }
  };

  stage(0, 0);
  int cur = 0;
  for (int t = 0; t < 16; ++t) {
    __syncthreads();
    if (t < 15) stage(cur ^ 1, t + 1);
    short8 ah[4], bh[4], al[4], bl[4];
#pragma unroll
    for (int m = 0; m < 4; ++m) {
      int r = wm * 64 + m * 16 + l15;
      int kb = (g << 4) ^ (((r >> 1) & 3) << 4);
      ah[m] = *(const short8*)&lds[cur][0][r * 32 + (kb >> 1)];
      if constexpr (NPROD == 3)
        al[m] = *(const short8*)&lds[cur][2][r * 32 + (kb >> 1)];
    }
#pragma unroll
    for (int n = 0; n < 4; ++n) {
      int r = wn * 64 + n * 16 + l15;
      int kb = (g << 4) ^ (((r >> 1) & 3) << 4);
      bh[n] = *(const short8*)&lds[cur][1][r * 32 + (kb >> 1)];
      if constexpr (NPROD == 3)
        bl[n] = *(const short8*)&lds[cur][3][r * 32 + (kb >> 1)];
    }
#pragma unroll
    for (int m = 0; m < 4; ++m)
#pragma unroll
      for (int n = 0; n < 4; ++n) {
        acc[m][n] = mfma16(ah[m], bh[n], acc[m][n]);
        if constexpr (NPROD == 3) {
          acc[m][n] = mfma16(ah[m], bl[n], acc[m][n]);
          acc[m][n] = mfma16(al[m], bh[n], acc[m][n]);
        }
      }
    cur ^= 1;
  }
#pragma unroll
  for (int m = 0; m < 4; ++m)
#pragma unroll
    for (int n = 0; n < 4; ++n)
#pragma unroll
      for (int q = 0; q < 4; ++q) {
        int row = row0 + wm * 64 + m * 16 + g * 4 + q;
        int col = col0 + wn * 64 + n * 16 + l15;
        float v = acc[m][n][q];
        size_t o = (size_t)row * ldc + col;
        if constexpr (WF) Cf[o] = v;
        if constexpr (WH) {
          ushort_t hb = bf16_rn(v);
          Ch[o] = hb;
          if constexpr (WL) Cl[o] = bf16_rn(v - bf16_f(hb));
        }
      }
}

// ---------------------------------------------------------------------------
// Routing GEMM: per (b,h): S = Q(4096x64) @ Pk(1024x64)^T, split-bf16,
// fused col-max epilogue -> atomicMax(route[b,c]). B-frags register-resident.
// LDS tiles are [128][64] bf16 (128B rows), swizzle byte ^= ((row&7)<<4).
// ---------------------------------------------------------------------------
__device__ __forceinline__ uint float_key(float f) {
  uint bits = __float_as_uint(f);
  return (bits & 0x80000000u) ? ~bits : (bits | 0x80000000u);
}

__device__ __forceinline__ void stage128x64(const ushort_t* src, int stride,
                                            ushort_t* dst, int wv, int lane) {
#pragma unroll
  for (int j = 0; j < 4; ++j) {
    int si = j * 256 + wv * 64 + lane;
    int row = si >> 3;
    int kb = ((si & 7) << 4) ^ ((row & 7) << 4);
    load_lds16(src + (size_t)row * stride + (kb >> 1),
               dst + (size_t)(j * 256 + wv * 64) * 8);
  }
}

__global__ __launch_bounds__(256) void route_mfma(
    const ushort_t* __restrict__ Qh, const ushort_t* __restrict__ Ql,
    const ushort_t* __restrict__ Pkh, const ushort_t* __restrict__ Pkl,
    uint* __restrict__ route) {
  __shared__ ushort_t Alds[2][2][128 * 64];  // [buf][hi/lo] 64 KB
  __shared__ ushort_t Blds[2][128 * 64];     // [hi/lo]      32 KB
  __shared__ float red[2][128];
  const int tid = threadIdx.x, lane = tid & 63, wv = tid >> 6;
  const int l15 = lane & 15, g = lane >> 4;
  const int wm = wv >> 1, wc = wv & 1;
  const int c0 = blockIdx.x * 128;
  const int h = blockIdx.y >> 1, sb = blockIdx.y & 1;
  const int b = blockIdx.z;
  const int s0 = sb * 2048;
  const ushort_t* Qhb = Qh + ((size_t)b * SEQ) * 512 + h * 64;
  const ushort_t* Qlb = Ql + ((size_t)b * SEQ) * 512 + h * 64;
  const ushort_t* Pkhb = Pkh + ((size_t)b * NCHUNK + c0) * 1024 + h * 64;
  const ushort_t* Pklb = Pkl + ((size_t)b * NCHUNK + c0) * 1024 + h * 64;

  stage128x64(Pkhb, 1024, &Blds[0][0], wv, lane);
  stage128x64(Pklb, 1024, &Blds[1][0], wv, lane);
  __syncthreads();
  short8 bh[2][4], bl[2][4];
#pragma unroll
  for (int kk = 0; kk < 2; ++kk)
#pragma unroll
    for (int n = 0; n < 4; ++n) {
      int r = wc * 64 + n * 16 + l15;
      int kb = (kk * 64 + (g << 4)) ^ ((r & 7) << 4);
      bh[kk][n] = *(const short8*)&Blds[0][r * 64 + (kb >> 1)];
      bl[kk][n] = *(const short8*)&Blds[1][r * 64 + (kb >> 1)];
    }

  float rmax[4] = {-1e30f, -1e30f, -1e30f, -1e30f};
  stage128x64(Qhb + (size_t)s0 * 512, 512, &Alds[0][0][0], wv, lane);
  stage128x64(Qlb + (size_t)s0 * 512, 512, &Alds[0][1][0], wv, lane);
  int cur = 0;
  for (int it = 0; it < 16; ++it) {
    __syncthreads();
    if (it < 15) {
      size_t so = (size_t)(s0 + (it + 1) * 128) * 512;
      stage128x64(Qhb + so, 512, &Alds[cur ^ 1][0][0], wv, lane);
      stage128x64(Qlb + so, 512, &Alds[cur ^ 1][1][0], wv, lane);
    }
    f32x4 acc[4][4];
#pragma unroll
    for (int m = 0; m < 4; ++m)
#pragma unroll
      for (int n = 0; n < 4; ++n) acc[m][n] = (f32x4){0.f, 0.f, 0.f, 0.f};
#pragma unroll
    for (int kk = 0; kk < 2; ++kk) {
      short8 ah[4], al[4];
#pragma unroll
      for (int m = 0; m < 4; ++m) {
        int r = wm * 64 + m * 16 + l15;
        int kb = (kk * 64 + (g << 4)) ^ ((r & 7) << 4);
        ah[m] = *(const short8*)&Alds[cur][0][r * 64 + (kb >> 1)];
        al[m] = *(const short8*)&Alds[cur][1][r * 64 + (kb >> 1)];
      }
#pragma unroll
      for (int m = 0; m < 4; ++m)
#pragma unroll
        for (int n = 0; n < 4; ++n) {
          acc[m][n] = mfma16(ah[m], bh[kk][n], acc[m][n]);
          acc[m][n] = mfma16(ah[m], bl[kk][n], acc[m][n]);
          acc[m][n] = mfma16(al[m], bh[kk][n], acc[m][n]);
        }
    }
#pragma unroll
    for (int n = 0; n < 4; ++n)
#pragma unroll
      for (int m = 0; m < 4; ++m)
        rmax[n] = fmaxf(rmax[n],
                        fmaxf(fmaxf(acc[m][n][0], acc[m][n][1]),
                              fmaxf(acc[m][n][2], acc[m][n][3])));
    cur ^= 1;
  }
#pragma unroll
  for (int n = 0; n < 4; ++n) {
    float v = rmax[n];
    v = fmaxf(v, __shfl_xor(v, 16, 64));
    v = fmaxf(v, __shfl_xor(v, 32, 64));
    if (g == 0) red[wm][wc * 64 + n * 16 + l15] = v;
  }
  __syncthreads();
  if (tid < 128) {
    float v = fmaxf(red[0][tid], red[1][tid]);
    atomicMax(&route[b * NCHUNK + c0 + tid], float_key(v));
  }
}

// ---------------------------------------------------------------------------
// Top-K per batch (iterative argmax; selected SET is what matters).
// ---------------------------------------------------------------------------
__global__ __launch_bounds__(256) void topk_kernel(const uint* __restrict__ route,
                                                   int* __restrict__ topidx) {
  const int b = blockIdx.x, tid = threadIdx.x;
  __shared__ unsigned long long keys[NCHUNK];
  __shared__ unsigned long long red[256];
#pragma unroll
  for (int i = 0; i < 4; ++i) {
    int idx = tid + i * 256;
    keys[idx] = ((unsigned long long)route[b * NCHUNK + idx] << 32) |
                (uint)(NCHUNK - 1 - idx);
  }
  __syncthreads();
  for (int it = 0; it < TOPK; ++it) {
    unsigned long long mx = keys[tid];
#pragma unroll
    for (int i = 1; i < 4; ++i) {
      unsigned long long k = keys[tid + i * 256];
      mx = (k > mx) ? k : mx;
    }
    red[tid] = mx;
    __syncthreads();
    for (int st = 128; st > 0; st >>= 1) {
      if (tid < st) {
        unsigned long long k = red[tid + st];
        if (k > red[tid]) red[tid] = k;
      }
      __syncthreads();
    }
    int widx = NCHUNK - 1 - (int)(red[0] & 0xffffffffu);
    if (tid == 0) {
      topidx[b * TOPK + it] = widx;
      keys[widx] = 0ULL;
    }
    __syncthreads();
  }
}

// ---------------------------------------------------------------------------
// Sparse attention: one wave per (b,s,h); Q/K reconstructed hi+lo (f32-grade),
// V hi+lo; output written as bf16 for the Wo MFMA GEMM.
// ---------------------------------------------------------------------------
__global__ __launch_bounds__(256) void attn_kernel(
    const ushort_t* __restrict__ Qh, const ushort_t* __restrict__ Ql,
    const ushort_t* __restrict__ Pkvh, const ushort_t* __restrict__ Pkvl,
    const int* __restrict__ topidx, ushort_t* __restrict__ AObf) {
  const int gw = (int)((blockIdx.x * 256 + threadIdx.x) >> 6);
  const int lane = threadIdx.x & 63;
  const int h = gw & 7;
  const int s = (gw >> 3) & (SEQ - 1);
  const int b = gw >> 15;
  const size_t qoff = ((size_t)(b * SEQ + s)) * 512 + h * HDIM + lane;
  const float q = bf16_f(Qh[qoff]) + bf16_f(Ql[qoff]);
  float sc[TOPK];
  size_t koff[TOPK];
  float m = -1e30f;
#pragma unroll
  for (int j = 0; j < TOPK; ++j) {
    int c = topidx[b * TOPK + j];
    koff[j] = ((size_t)(b * NCHUNK + c)) * 1024 + h * HDIM + lane;
    float kd = bf16_f(Pkvh[koff[j]]) + bf16_f(Pkvl[koff[j]]);
    float p = q * kd;
#pragma unroll
    for (int o = 32; o > 0; o >>= 1) p += __shfl_xor(p, o, 64);
    sc[j] = p * SCALING;
    m = fmaxf(m, sc[j]);
  }
  float se = 0.f, w[TOPK];
#pragma unroll
  for (int j = 0; j < TOPK; ++j) {
    w[j] = __expf(sc[j] - m);
    se += w[j];
  }
  const float inv = 1.f / se;
  float o = 0.f;
#pragma unroll
  for (int j = 0; j < TOPK; ++j)
    o += w[j] * (bf16_f(Pkvh[koff[j] + 512]) + bf16_f(Pkvl[koff[j] + 512]));
  AObf[qoff] = bf16_rn(o * inv);
}

// ---------------------------------------------------------------------------
extern "C" void kernel_launch(void* const* d_in, const int* in_sizes, int n_in,
                              void* d_out, int out_size, void* d_ws, size_t ws_size,
                              hipStream_t stream) {
  const float* H = (const float*)d_in[0];
  const float* Wq = (const float*)d_in[1];
  const float* Wk = (const float*)d_in[2];
  const float* Wv = (const float*)d_in[3];
  const float* Wo = (const float*)d_in[4];
  float* out = (float*)d_out;

  char* p = (char*)d_ws;
  auto alloc = [&](size_t bytes) {
    void* r = (void*)p;
    p += (bytes + 255) & ~(size_t)255;
    return r;
  };
  const size_t BS = (size_t)BATCH * SEQ;    // 16384
  const size_t BC = (size_t)BATCH * NCHUNK; // 4096
  ushort_t* Hh = (ushort_t*)alloc(BS * 512 * 2);
  ushort_t* Hl = (ushort_t*)alloc(BS * 512 * 2);
  ushort_t* Hph = (ushort_t*)alloc(BC * 512 * 2);
  ushort_t* Hpl = (ushort_t*)alloc(BC * 512 * 2);
  ushort_t* Wtq_h = (ushort_t*)alloc(512 * 512 * 2);
  ushort_t* Wtq_l = (ushort_t*)alloc(512 * 512 * 2);
  ushort_t* Wtkv_h = (ushort_t*)alloc(1024 * 512 * 2);
  ushort_t* Wtkv_l = (ushort_t*)alloc(1024 * 512 * 2);
  ushort_t* Wto_h = (ushort_t*)alloc(512 * 512 * 2);
  ushort_t* Wto_l = (ushort_t*)alloc(512 * 512 * 2);
  ushort_t* Qh = (ushort_t*)alloc(BS * 512 * 2);
  ushort_t* Ql = (ushort_t*)alloc(BS * 512 * 2);
  ushort_t* Pkvh = (ushort_t*)alloc(BC * 1024 * 2);
  ushort_t* Pkvl = (ushort_t*)alloc(BC * 1024 * 2);
  ushort_t* AObf = (ushort_t*)alloc(BS * 512 * 2);
  uint* route = (uint*)alloc(BC * 4);
  int* topidx = (int*)alloc(BATCH * TOPK * 4);

  // 1. weight transpose + split; hidden pool + split
  wtrans_kernel<<<dim3(8, 8, 4), 256, 0, stream>>>(
      Wq, Wk, Wv, Wo, Wtq_h, Wtq_l, Wtkv_h, Wtkv_l, Wto_h, Wto_l);
  pool_split_kernel<<<2048, 256, 0, stream>>>(H, Hh, Hl, Hph, Hpl);
  // 2. projections (split-bf16 MFMA): Q full-seq; K|V fused on pooled seq
  gemm_mfma<3, true, true, false><<<dim3(4, 128), 256, 0, stream>>>(
      Hh, Hl, Wtq_h, Wtq_l, Qh, Ql, nullptr, 512);
  gemm_mfma<3, true, true, false><<<dim3(8, 32), 256, 0, stream>>>(
      Hph, Hpl, Wtkv_h, Wtkv_l, Pkvh, Pkvl, nullptr, 1024);
  // 3. routing scores (split-bf16 MFMA, fused max epilogue)
  hipMemsetAsync(route, 0, BC * 4, stream);
  route_mfma<<<dim3(8, 16, 4), 256, 0, stream>>>(Qh, Ql, Pkvh, Pkvl, route);
  // 4. top-8 chunks per batch
  topk_kernel<<<BATCH, 256, 0, stream>>>(route, topidx);
  // 5. sparse attention -> bf16 activations
  attn_kernel<<<32768, 256, 0, stream>>>(Qh, Ql, Pkvh, Pkvl, topidx, AObf);
  // 6. output projection (plain bf16 MFMA)
  gemm_mfma<1, false, false, true><<<dim3(4, 128), 256, 0, stream>>>(
      AObf, nullptr, Wto_h, nullptr, nullptr, nullptr, out, 512);
  (void)in_sizes; (void)n_in; (void)out_size; (void)ws_size;
}

// Round 3
// 275.918 us; speedup vs baseline: 3.8174x; 1.0779x over previous
//
#include <hip/hip_runtime.h>

#define SEQ 4096
#define BATCH 4
#define EMB 512
#define NHEAD 8
#define HDIM 64
#define NCHUNK 1024
#define TOPK 8
#define NSEL 32
#define SCALING 0.125f

typedef unsigned int uint;
typedef unsigned short ushort_t;
typedef __attribute__((ext_vector_type(8))) short short8;
typedef __attribute__((ext_vector_type(4))) float f32x4;
typedef __attribute__((ext_vector_type(4))) unsigned short us4;
typedef __attribute__((ext_vector_type(8))) unsigned short us8;

// ---- bf16 split helpers (x ~= hi + lo, each bf16; RNE rounding) -----------
__device__ __forceinline__ ushort_t bf16_rn(float x) {
  uint b = __float_as_uint(x);
  return (ushort_t)((b + 0x7FFFu + ((b >> 16) & 1u)) >> 16);
}
__device__ __forceinline__ float bf16_f(ushort_t u) {
  return __uint_as_float(((uint)u) << 16);
}

// ---- async global->LDS, 16B per lane --------------------------------------
__device__ __forceinline__ void load_lds16(const void* g, void* l) {
  __builtin_amdgcn_global_load_lds(
      (const __attribute__((address_space(1))) unsigned int*)g,
      (__attribute__((address_space(3))) unsigned int*)l, 16, 0, 0);
}

__device__ __forceinline__ f32x4 mfma16(short8 a, short8 b, f32x4 c) {
  return __builtin_amdgcn_mfma_f32_16x16x32_bf16(a, b, c, 0, 0, 0);
}

// ---------------------------------------------------------------------------
// Weight prep: Wt[n][k] = W[k][n], split hi/lo bf16. z in {0:Wq, 1:Wk, 2:Wv}.
// ---------------------------------------------------------------------------
__global__ __launch_bounds__(256) void wtrans_kernel(
    const float* __restrict__ Wq, const float* __restrict__ Wk,
    const float* __restrict__ Wv,
    ushort_t* __restrict__ Wtq_h, ushort_t* __restrict__ Wtq_l,
    ushort_t* __restrict__ Wtkv_h, ushort_t* __restrict__ Wtkv_l) {
  __shared__ float t[64][65];
  const int z = blockIdx.z;
  const float* src = (z == 0) ? Wq : (z == 1) ? Wk : Wv;
  ushort_t* dh = (z == 0) ? Wtq_h : Wtkv_h;
  ushort_t* dl = (z == 0) ? Wtq_l : Wtkv_l;
  const size_t obase = (z == 2) ? (size_t)512 * 512 : 0;  // Wv rows 512..1023
  const int k0 = blockIdx.x * 64, n0 = blockIdx.y * 64;
  const int tid = threadIdx.x;
#pragma unroll
  for (int i = 0; i < 4; ++i) {
    int row = (tid >> 4) + i * 16, col = (tid & 15) * 4;
    float4 v = *(const float4*)&src[(size_t)(k0 + row) * 512 + n0 + col];
    t[row][col + 0] = v.x; t[row][col + 1] = v.y;
    t[row][col + 2] = v.z; t[row][col + 3] = v.w;
  }
  __syncthreads();
#pragma unroll
  for (int i = 0; i < 4; ++i) {
    int nrow = (tid >> 4) + i * 16, kcol = (tid & 15) * 4;
    us4 h, l;
#pragma unroll
    for (int j = 0; j < 4; ++j) {
      float v = t[kcol + j][nrow];
      ushort_t hb = bf16_rn(v);
      h[j] = hb;
      l[j] = bf16_rn(v - bf16_f(hb));
    }
    size_t o = obase + (size_t)(n0 + nrow) * 512 + k0 + kcol;
    *(us4*)&dh[o] = h;
    *(us4*)&dl[o] = l;
  }
}

// ---------------------------------------------------------------------------
// Pool + split: H (f32) -> Hh/Hl (bf16 split) and chunk-mean -> Hph/Hpl.
// ---------------------------------------------------------------------------
__global__ __launch_bounds__(256) void pool_split_kernel(
    const float* __restrict__ H, ushort_t* __restrict__ Hh,
    ushort_t* __restrict__ Hl, ushort_t* __restrict__ Hph,
    ushort_t* __restrict__ Hpl) {
  const int idx = blockIdx.x * 256 + threadIdx.x;  // < 4*1024*128
  const int e4 = (idx & 127) << 2;
  const int c = (idx >> 7) & 1023;
  const int b = idx >> 17;
  const size_t rbase = ((size_t)(b * SEQ + c * 4)) * 512 + e4;
  float4 s = make_float4(0.f, 0.f, 0.f, 0.f);
#pragma unroll
  for (int j = 0; j < 4; ++j) {
    float4 v = *(const float4*)&H[rbase + (size_t)j * 512];
    s.x += v.x; s.y += v.y; s.z += v.z; s.w += v.w;
    us4 h, l;
    float a[4] = {v.x, v.y, v.z, v.w};
#pragma unroll
    for (int q = 0; q < 4; ++q) {
      ushort_t hb = bf16_rn(a[q]);
      h[q] = hb;
      l[q] = bf16_rn(a[q] - bf16_f(hb));
    }
    *(us4*)&Hh[rbase + (size_t)j * 512] = h;
    *(us4*)&Hl[rbase + (size_t)j * 512] = l;
  }
  float a[4] = {s.x * 0.25f, s.y * 0.25f, s.z * 0.25f, s.w * 0.25f};
  us4 h, l;
#pragma unroll
  for (int q = 0; q < 4; ++q) {
    ushort_t hb = bf16_rn(a[q]);
    h[q] = hb;
    l[q] = bf16_rn(a[q] - bf16_f(hb));
  }
  size_t po = ((size_t)(b * NCHUNK + c)) * 512 + e4;
  *(us4*)&Hph[po] = h;
  *(us4*)&Hpl[po] = l;
}

// ---------------------------------------------------------------------------
// MFMA GEMM (projections): C(M,N) = A(M,512) @ Bt(N,512)^T, split-bf16,
// 3 products (AhBh+AhBl+AlBh). Tile 128x128, BK=32, double-buffered LDS,
// global_load_lds(16B), XOR swizzle (2-way conflicts max).
// ---------------------------------------------------------------------------
__global__ __launch_bounds__(256) void gemm_mfma3(
    const ushort_t* __restrict__ Ah, const ushort_t* __restrict__ Al,
    const ushort_t* __restrict__ Bh, const ushort_t* __restrict__ Bl,
    ushort_t* __restrict__ Ch, ushort_t* __restrict__ Cl, int ldc) {
  __shared__ ushort_t lds[2][4][4096];  // [buf][Ah,Bh,Al,Bl][128*32]
  const int tid = threadIdx.x, lane = tid & 63, wv = tid >> 6;
  const int l15 = lane & 15, g = lane >> 4;
  const int wm = wv >> 1, wn = wv & 1;
  const int row0 = blockIdx.y * 128, col0 = blockIdx.x * 128;
  const ushort_t* A0 = Ah + (size_t)row0 * 512;
  const ushort_t* B0 = Bh + (size_t)col0 * 512;
  const ushort_t* A1 = Al + (size_t)row0 * 512;
  const ushort_t* B1 = Bl + (size_t)col0 * 512;
  f32x4 acc[4][4];
#pragma unroll
  for (int m = 0; m < 4; ++m)
#pragma unroll
    for (int n = 0; n < 4; ++n) acc[m][n] = (f32x4){0.f, 0.f, 0.f, 0.f};

  auto stage = [&](int buf, int t) {
#pragma unroll
    for (int j = 0; j < 2; ++j) {
      int si = j * 256 + wv * 64 + lane;
      int row = si >> 2;
      int kb = ((si & 3) << 4) ^ (((row >> 1) & 3) << 4);
      size_t goff = (size_t)row * 512 + t * 32 + (kb >> 1);
      int doff = (j * 256 + wv * 64) * 8;
      load_lds16(A0 + goff, &lds[buf][0][doff]);
      load_lds16(B0 + goff, &lds[buf][1][doff]);
      load_lds16(A1 + goff, &lds[buf][2][doff]);
      load_lds16(B1 + goff, &lds[buf][3][doff]);
    }
  };

  stage(0, 0);
  int cur = 0;
  for (int t = 0; t < 16; ++t) {
    __syncthreads();
    if (t < 15) stage(cur ^ 1, t + 1);
    short8 ah[4], bh[4], al[4], bl[4];
#pragma unroll
    for (int m = 0; m < 4; ++m) {
      int r = wm * 64 + m * 16 + l15;
      int kb = (g << 4) ^ (((r >> 1) & 3) << 4);
      ah[m] = *(const short8*)&lds[cur][0][r * 32 + (kb >> 1)];
      al[m] = *(const short8*)&lds[cur][2][r * 32 + (kb >> 1)];
    }
#pragma unroll
    for (int n = 0; n < 4; ++n) {
      int r = wn * 64 + n * 16 + l15;
      int kb = (g << 4) ^ (((r >> 1) & 3) << 4);
      bh[n] = *(const short8*)&lds[cur][1][r * 32 + (kb >> 1)];
      bl[n] = *(const short8*)&lds[cur][3][r * 32 + (kb >> 1)];
    }
#pragma unroll
    for (int m = 0; m < 4; ++m)
#pragma unroll
      for (int n = 0; n < 4; ++n) {
        acc[m][n] = mfma16(ah[m], bh[n], acc[m][n]);
        acc[m][n] = mfma16(ah[m], bl[n], acc[m][n]);
        acc[m][n] = mfma16(al[m], bh[n], acc[m][n]);
      }
    cur ^= 1;
  }
#pragma unroll
  for (int m = 0; m < 4; ++m)
#pragma unroll
    for (int n = 0; n < 4; ++n)
#pragma unroll
      for (int q = 0; q < 4; ++q) {
        int row = row0 + wm * 64 + m * 16 + g * 4 + q;
        int col = col0 + wn * 64 + n * 16 + l15;
        float v = acc[m][n][q];
        size_t o = (size_t)row * ldc + col;
        ushort_t hb = bf16_rn(v);
        Ch[o] = hb;
        Cl[o] = bf16_rn(v - bf16_f(hb));
      }
}

// ---------------------------------------------------------------------------
// Routing GEMM: per (b,h): S = Q(4096x64) @ Pk^T, fused col-max epilogue ->
// atomicMax. NPROD=1: bf16 screen over all chunks. NPROD=3: exact rescore
// over a compact gathered candidate set (kstride=512, ncap=128).
// ---------------------------------------------------------------------------
__device__ __forceinline__ uint float_key(float f) {
  uint bits = __float_as_uint(f);
  return (bits & 0x80000000u) ? ~bits : (bits | 0x80000000u);
}

__device__ __forceinline__ void stage128x64(const ushort_t* src, int stride,
                                            ushort_t* dst, int wv, int lane) {
#pragma unroll
  for (int j = 0; j < 4; ++j) {
    int si = j * 256 + wv * 64 + lane;
    int row = si >> 3;
    int kb = ((si & 7) << 4) ^ ((row & 7) << 4);
    load_lds16(src + (size_t)row * stride + (kb >> 1),
               dst + (size_t)(j * 256 + wv * 64) * 8);
  }
}

template <int NPROD>
__global__ __launch_bounds__(256) void route_mfma(
    const ushort_t* __restrict__ Qh, const ushort_t* __restrict__ Ql,
    const ushort_t* __restrict__ Pkh, const ushort_t* __restrict__ Pkl,
    int kstride, int ncap, uint* __restrict__ route) {
  constexpr int NB = (NPROD == 3) ? 2 : 1;
  __shared__ ushort_t Alds[2][NB][128 * 64];
  __shared__ ushort_t Blds[NB][128 * 64];
  __shared__ float red[2][128];
  const int tid = threadIdx.x, lane = tid & 63, wv = tid >> 6;
  const int l15 = lane & 15, g = lane >> 4;
  const int wm = wv >> 1, wc = wv & 1;
  const int c0 = blockIdx.x * 128;
  const int h = blockIdx.y >> 1, sb = blockIdx.y & 1;
  const int b = blockIdx.z;
  const int s0 = sb * 2048;
  const ushort_t* Qhb = Qh + ((size_t)b * SEQ) * 512 + h * 64;
  const ushort_t* Qlb = Ql + ((size_t)b * SEQ) * 512 + h * 64;
  const ushort_t* Pkhb = Pkh + ((size_t)(b * ncap + c0)) * kstride + h * 64;
  const ushort_t* Pklb = Pkl + ((size_t)(b * ncap + c0)) * kstride + h * 64;

  stage128x64(Pkhb, kstride, &Blds[0][0], wv, lane);
  if constexpr (NPROD == 3) stage128x64(Pklb, kstride, &Blds[1][0], wv, lane);
  __syncthreads();
  short8 bh[2][4], bl[2][4];
#pragma unroll
  for (int kk = 0; kk < 2; ++kk)
#pragma unroll
    for (int n = 0; n < 4; ++n) {
      int r = wc * 64 + n * 16 + l15;
      int kb = (kk * 64 + (g << 4)) ^ ((r & 7) << 4);
      bh[kk][n] = *(const short8*)&Blds[0][r * 64 + (kb >> 1)];
      if constexpr (NPROD == 3)
        bl[kk][n] = *(const short8*)&Blds[1][r * 64 + (kb >> 1)];
    }

  float rmax[4] = {-1e30f, -1e30f, -1e30f, -1e30f};
  stage128x64(Qhb + (size_t)s0 * 512, 512, &Alds[0][0][0], wv, lane);
  if constexpr (NPROD == 3)
    stage128x64(Qlb + (size_t)s0 * 512, 512, &Alds[0][1][0], wv, lane);
  int cur = 0;
  for (int it = 0; it < 16; ++it) {
    __syncthreads();
    if (it < 15) {
      size_t so = (size_t)(s0 + (it + 1) * 128) * 512;
      stage128x64(Qhb + so, 512, &Alds[cur ^ 1][0][0], wv, lane);
      if constexpr (NPROD == 3)
        stage128x64(Qlb + so, 512, &Alds[cur ^ 1][1][0], wv, lane);
    }
    f32x4 acc[4][4];
#pragma unroll
    for (int m = 0; m < 4; ++m)
#pragma unroll
      for (int n = 0; n < 4; ++n) acc[m][n] = (f32x4){0.f, 0.f, 0.f, 0.f};
#pragma unroll
    for (int kk = 0; kk < 2; ++kk) {
      short8 ah[4], al[4];
#pragma unroll
      for (int m = 0; m < 4; ++m) {
        int r = wm * 64 + m * 16 + l15;
        int kb = (kk * 64 + (g << 4)) ^ ((r & 7) << 4);
        ah[m] = *(const short8*)&Alds[cur][0][r * 64 + (kb >> 1)];
        if constexpr (NPROD == 3)
          al[m] = *(const short8*)&Alds[cur][1][r * 64 + (kb >> 1)];
      }
#pragma unroll
      for (int m = 0; m < 4; ++m)
#pragma unroll
        for (int n = 0; n < 4; ++n) {
          acc[m][n] = mfma16(ah[m], bh[kk][n], acc[m][n]);
          if constexpr (NPROD == 3) {
            acc[m][n] = mfma16(ah[m], bl[kk][n], acc[m][n]);
            acc[m][n] = mfma16(al[m], bh[kk][n], acc[m][n]);
          }
        }
    }
#pragma unroll
    for (int n = 0; n < 4; ++n)
#pragma unroll
      for (int m = 0; m < 4; ++m)
        rmax[n] = fmaxf(rmax[n],
                        fmaxf(fmaxf(acc[m][n][0], acc[m][n][1]),
                              fmaxf(acc[m][n][2], acc[m][n][3])));
    cur ^= 1;
  }
#pragma unroll
  for (int n = 0; n < 4; ++n) {
    float v = rmax[n];
    v = fmaxf(v, __shfl_xor(v, 16, 64));
    v = fmaxf(v, __shfl_xor(v, 32, 64));
    if (g == 0) red[wm][wc * 64 + n * 16 + l15] = v;
  }
  __syncthreads();
  if (tid < 128) {
    float v = fmaxf(red[0][tid], red[1][tid]);
    atomicMax(&route[b * ncap + c0 + tid], float_key(v));
  }
}

// ---------------------------------------------------------------------------
// Top-NSEL candidate selection per batch (iterative argmax over 1024 keys).
// ---------------------------------------------------------------------------
__global__ __launch_bounds__(256) void topk_sel(const uint* __restrict__ route,
                                                int* __restrict__ cand) {
  const int b = blockIdx.x, tid = threadIdx.x;
  __shared__ unsigned long long keys[NCHUNK];
  __shared__ unsigned long long red[256];
#pragma unroll
  for (int i = 0; i < 4; ++i) {
    int idx = tid + i * 256;
    keys[idx] = ((unsigned long long)route[b * NCHUNK + idx] << 32) |
                (uint)(NCHUNK - 1 - idx);
  }
  __syncthreads();
  for (int it = 0; it < NSEL; ++it) {
    unsigned long long mx = keys[tid];
#pragma unroll
    for (int i = 1; i < 4; ++i) {
      unsigned long long k = keys[tid + i * 256];
      mx = (k > mx) ? k : mx;
    }
    red[tid] = mx;
    __syncthreads();
    for (int st = 128; st > 0; st >>= 1) {
      if (tid < st) {
        unsigned long long k = red[tid + st];
        if (k > red[tid]) red[tid] = k;
      }
      __syncthreads();
    }
    int widx = NCHUNK - 1 - (int)(red[0] & 0xffffffffu);
    if (tid == 0) {
      cand[b * NSEL + it] = widx;
      keys[widx] = 0ULL;
    }
    __syncthreads();
  }
}

// ---------------------------------------------------------------------------
// Gather K-halves of the NSEL candidate chunks into compact Pkc[b][128][512]
// (rows >= NSEL zero-filled; their scores lose to any real chunk).
// ---------------------------------------------------------------------------
__global__ __launch_bounds__(256) void gather_kernel(
    const ushort_t* __restrict__ Pkvh, const ushort_t* __restrict__ Pkvl,
    const int* __restrict__ cand, ushort_t* __restrict__ Pkch,
    ushort_t* __restrict__ Pkcl) {
  const int row = blockIdx.x, b = blockIdx.y, tid = threadIdx.x;
  size_t dst = ((size_t)(b * 128 + row)) * 512;
  if (row < NSEL) {
    int c = cand[b * NSEL + row];
    size_t src = ((size_t)(b * NCHUNK + c)) * 1024;
#pragma unroll
    for (int i = 0; i < 2; ++i) {
      Pkch[dst + tid + i * 256] = Pkvh[src + tid + i * 256];
      Pkcl[dst + tid + i * 256] = Pkvl[src + tid + i * 256];
    }
  } else {
#pragma unroll
    for (int i = 0; i < 2; ++i) {
      Pkch[dst + tid + i * 256] = 0;
      Pkcl[dst + tid + i * 256] = 0;
    }
  }
}

// ---------------------------------------------------------------------------
// Final top-8 among the NSEL exactly-rescored candidates.
// ---------------------------------------------------------------------------
__global__ __launch_bounds__(64) void topk_final(const uint* __restrict__ route2,
                                                 const int* __restrict__ cand,
                                                 int* __restrict__ topidx) {
  const int b = blockIdx.x, lane = threadIdx.x;
  uint key = (lane < NSEL) ? route2[b * 128 + lane] : 0u;
  const int myc = (lane < NSEL) ? cand[b * NSEL + lane] : 0;
  for (int it = 0; it < TOPK; ++it) {
    unsigned long long kk =
        ((unsigned long long)key << 32) | (uint)(63 - lane);
#pragma unroll
    for (int o = 32; o > 0; o >>= 1) {
      unsigned long long ot = __shfl_xor(kk, o, 64);
      kk = (ot > kk) ? ot : kk;
    }
    int widx = 63 - (int)(kk & 0xffffffffu);
    if (lane == widx) {
      topidx[b * TOPK + it] = myc;
      key = 0u;
    }
  }
}

// ---------------------------------------------------------------------------
// Softmax weights P[b,s,h*8+j]: one thread per (b,s,h); K_sel broadcast from
// LDS (f32, hi+lo reconstructed); no cross-lane ops at all. Split-bf16 out.
// ---------------------------------------------------------------------------
__global__ __launch_bounds__(256) void attn_p_kernel(
    const ushort_t* __restrict__ Qh, const ushort_t* __restrict__ Ql,
    const ushort_t* __restrict__ Pkvh, const ushort_t* __restrict__ Pkvl,
    const int* __restrict__ topidx, ushort_t* __restrict__ Ph,
    ushort_t* __restrict__ Pl) {
  __shared__ float Ksel[8][64];
  const int tid = threadIdx.x;
  const int st = blockIdx.x, h = blockIdx.y, b = blockIdx.z;
  if (tid < 128) {
    int j = tid >> 4, part = tid & 15;
    int c = topidx[b * TOPK + j];
    size_t base = ((size_t)(b * NCHUNK + c)) * 1024 + h * 64 + part * 4;
#pragma unroll
    for (int q = 0; q < 4; ++q)
      Ksel[j][part * 4 + q] = bf16_f(Pkvh[base + q]) + bf16_f(Pkvl[base + q]);
  }
  __syncthreads();
  const int s = st * 256 + tid;
  const size_t qbase = ((size_t)(b * SEQ + s)) * 512 + h * 64;
  float qf[64];
#pragma unroll
  for (int i = 0; i < 8; ++i) {
    us8 vh = *(const us8*)&Qh[qbase + i * 8];
    us8 vl = *(const us8*)&Ql[qbase + i * 8];
#pragma unroll
    for (int k = 0; k < 8; ++k) qf[i * 8 + k] = bf16_f(vh[k]) + bf16_f(vl[k]);
  }
  float sc[TOPK], m = -1e30f;
#pragma unroll
  for (int j = 0; j < TOPK; ++j) {
    float dot = 0.f;
#pragma unroll
    for (int d4 = 0; d4 < 16; ++d4) {
      float4 kv = *(const float4*)&Ksel[j][d4 * 4];
      dot += qf[d4 * 4 + 0] * kv.x + qf[d4 * 4 + 1] * kv.y +
             qf[d4 * 4 + 2] * kv.z + qf[d4 * 4 + 3] * kv.w;
    }
    sc[j] = dot * SCALING;
    m = fmaxf(m, sc[j]);
  }
  float se = 0.f, w8[TOPK];
#pragma unroll
  for (int j = 0; j < TOPK; ++j) {
    w8[j] = __expf(sc[j] - m);
    se += w8[j];
  }
  const float inv = 1.f / se;
  us8 ph8, pl8;
#pragma unroll
  for (int j = 0; j < TOPK; ++j) {
    float pv = w8[j] * inv;
    ushort_t hb = bf16_rn(pv);
    ph8[j] = hb;
    pl8[j] = bf16_rn(pv - bf16_f(hb));
  }
  size_t po = ((size_t)(b * SEQ + s)) * 64 + h * 8;
  *(us8*)&Ph[po] = ph8;
  *(us8*)&Pl[po] = pl8;
}

// ---------------------------------------------------------------------------
// VW[b][h*8+j][e] = sum_d V_sel[b,j,h,d] * Wo[h*64+d][e]; stored transposed
// (VWt[b][e][hj]) split hi/lo for the PVW MFMA B-operand. 16.8 MFLOP.
// ---------------------------------------------------------------------------
__global__ __launch_bounds__(256) void vw_kernel(
    const ushort_t* __restrict__ Pkvh, const ushort_t* __restrict__ Pkvl,
    const float* __restrict__ Wo, const int* __restrict__ topidx,
    ushort_t* __restrict__ VWth, ushort_t* __restrict__ VWtl) {
  __shared__ float Vs[8][512];
  const int tid = threadIdx.x, et = blockIdx.x, b = blockIdx.y;
#pragma unroll
  for (int i = 0; i < 16; ++i) {
    int idx = tid + i * 256;  // < 4096
    int j = idx >> 9, d = idx & 511;
    int c = topidx[b * TOPK + j];
    size_t src = ((size_t)(b * NCHUNK + c)) * 1024 + 512 + d;
    Vs[j][d] = bf16_f(Pkvh[src]) + bf16_f(Pkvl[src]);
  }
  __syncthreads();
  const int e = et * 64 + (tid & 63), qr = tid >> 6;
  ushort_t hbuf[16], lbuf[16];
#pragma unroll
  for (int i = 0; i < 16; ++i) {
    int hj = qr * 16 + i, h = hj >> 3, j = hj & 7;
    float dot = 0.f;
#pragma unroll
    for (int d = 0; d < 64; ++d)
      dot += Vs[j][h * 64 + d] * Wo[(size_t)(h * 64 + d) * 512 + e];
    ushort_t hb = bf16_rn(dot);
    hbuf[i] = hb;
    lbuf[i] = bf16_rn(dot - bf16_f(hb));
  }
  size_t o = ((size_t)(b * 512 + e)) * 64 + qr * 16;
  *(us8*)&VWth[o] = *(us8*)&hbuf[0];
  *(us8*)&VWth[o + 8] = *(us8*)&hbuf[8];
  *(us8*)&VWtl[o] = *(us8*)&lbuf[0];
  *(us8*)&VWtl[o + 8] = *(us8*)&lbuf[8];
}

// ---------------------------------------------------------------------------
// out(16384,512) = P(16384,64) @ VW_b(64,512): split-bf16, 3 products, f32 out.
// Tile 128x128, K=64 (2 steps of 32). Replaces PV + the whole Wo GEMM.
// ---------------------------------------------------------------------------
__global__ __launch_bounds__(256) void pvw_gemm(
    const ushort_t* __restrict__ Ph, const ushort_t* __restrict__ Pl,
    const ushort_t* __restrict__ VWth, const ushort_t* __restrict__ VWtl,
    float* __restrict__ out) {
  __shared__ ushort_t lds[2][4][4096];
  const int tid = threadIdx.x, lane = tid & 63, wv = tid >> 6;
  const int l15 = lane & 15, g = lane >> 4;
  const int wm = wv >> 1, wn = wv & 1;
  const int row0 = blockIdx.y * 128, col0 = blockIdx.x * 128;
  const int b = row0 >> 12;
  const ushort_t* A0 = Ph + (size_t)row0 * 64;
  const ushort_t* A1 = Pl + (size_t)row0 * 64;
  const ushort_t* B0 = VWth + ((size_t)(b * 512 + col0)) * 64;
  const ushort_t* B1 = VWtl + ((size_t)(b * 512 + col0)) * 64;
  f32x4 acc[4][4];
#pragma unroll
  for (int m = 0; m < 4; ++m)
#pragma unroll
    for (int n = 0; n < 4; ++n) acc[m][n] = (f32x4){0.f, 0.f, 0.f, 0.f};

  auto stage = [&](int buf, int t) {
#pragma unroll
    for (int j = 0; j < 2; ++j) {
      int si = j * 256 + wv * 64 + lane;
      int row = si >> 2;
      int kb = ((si & 3) << 4) ^ (((row >> 1) & 3) << 4);
      size_t goff = (size_t)row * 64 + t * 32 + (kb >> 1);
      int doff = (j * 256 + wv * 64) * 8;
      load_lds16(A0 + goff, &lds[buf][0][doff]);
      load_lds16(B0 + goff, &lds[buf][1][doff]);
      load_lds16(A1 + goff, &lds[buf][2][doff]);
      load_lds16(B1 + goff, &lds[buf][3][doff]);
    }
  };

  stage(0, 0);
  for (int t = 0; t < 2; ++t) {
    __syncthreads();
    if (t == 0) stage(1, 1);
    short8 ah[4], bh[4], al[4], bl[4];
#pragma unroll
    for (int m = 0; m < 4; ++m) {
      int r = wm * 64 + m * 16 + l15;
      int kb = (g << 4) ^ (((r >> 1) & 3) << 4);
      ah[m] = *(const short8*)&lds[t][0][r * 32 + (kb >> 1)];
      al[m] = *(const short8*)&lds[t][2][r * 32 + (kb >> 1)];
    }
#pragma unroll
    for (int n = 0; n < 4; ++n) {
      int r = wn * 64 + n * 16 + l15;
      int kb = (g << 4) ^ (((r >> 1) & 3) << 4);
      bh[n] = *(const short8*)&lds[t][1][r * 32 + (kb >> 1)];
      bl[n] = *(const short8*)&lds[t][3][r * 32 + (kb >> 1)];
    }
#pragma unroll
    for (int m = 0; m < 4; ++m)
#pragma unroll
      for (int n = 0; n < 4; ++n) {
        acc[m][n] = mfma16(ah[m], bh[n], acc[m][n]);
        acc[m][n] = mfma16(ah[m], bl[n], acc[m][n]);
        acc[m][n] = mfma16(al[m], bh[n], acc[m][n]);
      }
  }
#pragma unroll
  for (int m = 0; m < 4; ++m)
#pragma unroll
    for (int n = 0; n < 4; ++n)
#pragma unroll
      for (int q = 0; q < 4; ++q) {
        int row = row0 + wm * 64 + m * 16 + g * 4 + q;
        int col = col0 + wn * 64 + n * 16 + l15;
        out[(size_t)row * 512 + col] = acc[m][n][q];
      }
}

// ---------------------------------------------------------------------------
extern "C" void kernel_launch(void* const* d_in, const int* in_sizes, int n_in,
                              void* d_out, int out_size, void* d_ws, size_t ws_size,
                              hipStream_t stream) {
  const float* H = (const float*)d_in[0];
  const float* Wq = (const float*)d_in[1];
  const float* Wk = (const float*)d_in[2];
  const float* Wv = (const float*)d_in[3];
  const float* Wo = (const float*)d_in[4];
  float* out = (float*)d_out;

  char* p = (char*)d_ws;
  auto alloc = [&](size_t bytes) {
    void* r = (void*)p;
    p += (bytes + 255) & ~(size_t)255;
    return r;
  };
  const size_t BS = (size_t)BATCH * SEQ;     // 16384
  const size_t BC = (size_t)BATCH * NCHUNK;  // 4096
  ushort_t* Hh = (ushort_t*)alloc(BS * 512 * 2);
  ushort_t* Hl = (ushort_t*)alloc(BS * 512 * 2);
  ushort_t* Hph = (ushort_t*)alloc(BC * 512 * 2);
  ushort_t* Hpl = (ushort_t*)alloc(BC * 512 * 2);
  ushort_t* Wtq_h = (ushort_t*)alloc(512 * 512 * 2);
  ushort_t* Wtq_l = (ushort_t*)alloc(512 * 512 * 2);
  ushort_t* Wtkv_h = (ushort_t*)alloc(1024 * 512 * 2);
  ushort_t* Wtkv_l = (ushort_t*)alloc(1024 * 512 * 2);
  ushort_t* Qh = (ushort_t*)alloc(BS * 512 * 2);
  ushort_t* Ql = (ushort_t*)alloc(BS * 512 * 2);
  ushort_t* Pkvh = (ushort_t*)alloc(BC * 1024 * 2);
  ushort_t* Pkvl = (ushort_t*)alloc(BC * 1024 * 2);
  ushort_t* Pkch = (ushort_t*)alloc((size_t)BATCH * 128 * 512 * 2);
  ushort_t* Pkcl = (ushort_t*)alloc((size_t)BATCH * 128 * 512 * 2);
  ushort_t* Ph = (ushort_t*)alloc(BS * 64 * 2);
  ushort_t* Pl = (ushort_t*)alloc(BS * 64 * 2);
  ushort_t* VWth = (ushort_t*)alloc((size_t)BATCH * 512 * 64 * 2);
  ushort_t* VWtl = (ushort_t*)alloc((size_t)BATCH * 512 * 64 * 2);
  uint* route = (uint*)alloc(BC * 4);
  uint* route2 = (uint*)alloc((size_t)BATCH * 128 * 4);
  int* cand = (int*)alloc(BATCH * NSEL * 4);
  int* topidx = (int*)alloc(BATCH * TOPK * 4);

  // 1. weight transpose/split; hidden pool/split
  wtrans_kernel<<<dim3(8, 8, 3), 256, 0, stream>>>(
      Wq, Wk, Wv, Wtq_h, Wtq_l, Wtkv_h, Wtkv_l);
  pool_split_kernel<<<2048, 256, 0, stream>>>(H, Hh, Hl, Hph, Hpl);
  // 2. projections (split-bf16 MFMA): Q full-seq; K|V fused on pooled seq
  gemm_mfma3<<<dim3(4, 128), 256, 0, stream>>>(Hh, Hl, Wtq_h, Wtq_l, Qh, Ql, 512);
  gemm_mfma3<<<dim3(8, 32), 256, 0, stream>>>(Hph, Hpl, Wtkv_h, Wtkv_l, Pkvh,
                                              Pkvl, 1024);
  // 3. routing: bf16 screen -> top-32 candidates -> exact rescore -> top-8
  hipMemsetAsync(route, 0, BC * 4, stream);
  hipMemsetAsync(route2, 0, (size_t)BATCH * 128 * 4, stream);
  route_mfma<1><<<dim3(8, 16, 4), 256, 0, stream>>>(Qh, nullptr, Pkvh, nullptr,
                                                    1024, 1024, route);
  topk_sel<<<BATCH, 256, 0, stream>>>(route, cand);
  gather_kernel<<<dim3(128, BATCH), 256, 0, stream>>>(Pkvh, Pkvl, cand, Pkch,
                                                      Pkcl);
  route_mfma<3><<<dim3(1, 16, 4), 256, 0, stream>>>(Qh, Ql, Pkch, Pkcl, 512,
                                                    128, route2);
  topk_final<<<BATCH, 64, 0, stream>>>(route2, cand, topidx);
  // 4. softmax weights P (no PV, no shuffles)
  attn_p_kernel<<<dim3(16, 8, 4), 256, 0, stream>>>(Qh, Ql, Pkvh, Pkvl, topidx,
                                                    Ph, Pl);
  // 5. VW = V_sel @ Wo (tiny), then out = P @ VW (fused PV+Wo projection)
  vw_kernel<<<dim3(8, BATCH), 256, 0, stream>>>(Pkvh, Pkvl, Wo, topidx, VWth,
                                                VWtl);
  pvw_gemm<<<dim3(4, 128), 256, 0, stream>>>(Ph, Pl, VWth, VWtl, out);
  (void)in_sizes; (void)n_in; (void)out_size; (void)ws_size;
}

// Round 4
// 256.746 us; speedup vs baseline: 4.1025x; 1.0747x over previous
//
#include <hip/hip_runtime.h>

#define SEQ 4096
#define BATCH 4
#define EMB 512
#define NHEAD 8
#define HDIM 64
#define NCHUNK 1024
#define TOPK 8
#define NSEL 32
#define SCALING 0.125f

typedef unsigned int uint;
typedef unsigned short ushort_t;
typedef __attribute__((ext_vector_type(8))) short short8;
typedef __attribute__((ext_vector_type(4))) float f32x4;
typedef __attribute__((ext_vector_type(4))) unsigned short us4;
typedef __attribute__((ext_vector_type(8))) unsigned short us8;

// ---- bf16 split helpers (x ~= hi + lo, each bf16; RNE rounding) -----------
__device__ __forceinline__ ushort_t bf16_rn(float x) {
  uint b = __float_as_uint(x);
  return (ushort_t)((b + 0x7FFFu + ((b >> 16) & 1u)) >> 16);
}
__device__ __forceinline__ float bf16_f(ushort_t u) {
  return __uint_as_float(((uint)u) << 16);
}

// ---- async global->LDS, 16B per lane (dst = wave base + lane*16) ----------
__device__ __forceinline__ void load_lds16(const void* g, void* l) {
  __builtin_amdgcn_global_load_lds(
      (const __attribute__((address_space(1))) unsigned int*)g,
      (__attribute__((address_space(3))) unsigned int*)l, 16, 0, 0);
}

__device__ __forceinline__ f32x4 mfma16(short8 a, short8 b, f32x4 c) {
  return __builtin_amdgcn_mfma_f32_16x16x32_bf16(a, b, c, 0, 0, 0);
}

__device__ __forceinline__ uint float_key(float f) {
  uint bits = __float_as_uint(f);
  return (bits & 0x80000000u) ? ~bits : (bits | 0x80000000u);
}

// ---------------------------------------------------------------------------
// Weight prep: Wt[n][k] = W[k][n], split hi/lo bf16. z in {0:Wq, 1:Wk, 2:Wv}.
// ---------------------------------------------------------------------------
__global__ __launch_bounds__(256) void wtrans_kernel(
    const float* __restrict__ Wq, const float* __restrict__ Wk,
    const float* __restrict__ Wv,
    ushort_t* __restrict__ Wtq_h, ushort_t* __restrict__ Wtq_l,
    ushort_t* __restrict__ Wtkv_h, ushort_t* __restrict__ Wtkv_l) {
  __shared__ float t[64][65];
  const int z = blockIdx.z;
  const float* src = (z == 0) ? Wq : (z == 1) ? Wk : Wv;
  ushort_t* dh = (z == 0) ? Wtq_h : Wtkv_h;
  ushort_t* dl = (z == 0) ? Wtq_l : Wtkv_l;
  const size_t obase = (z == 2) ? (size_t)512 * 512 : 0;  // Wv rows 512..1023
  const int k0 = blockIdx.x * 64, n0 = blockIdx.y * 64;
  const int tid = threadIdx.x;
#pragma unroll
  for (int i = 0; i < 4; ++i) {
    int row = (tid >> 4) + i * 16, col = (tid & 15) * 4;
    float4 v = *(const float4*)&src[(size_t)(k0 + row) * 512 + n0 + col];
    t[row][col + 0] = v.x; t[row][col + 1] = v.y;
    t[row][col + 2] = v.z; t[row][col + 3] = v.w;
  }
  __syncthreads();
#pragma unroll
  for (int i = 0; i < 4; ++i) {
    int nrow = (tid >> 4) + i * 16, kcol = (tid & 15) * 4;
    us4 h, l;
#pragma unroll
    for (int j = 0; j < 4; ++j) {
      float v = t[kcol + j][nrow];
      ushort_t hb = bf16_rn(v);
      h[j] = hb;
      l[j] = bf16_rn(v - bf16_f(hb));
    }
    size_t o = obase + (size_t)(n0 + nrow) * 512 + k0 + kcol;
    *(us4*)&dh[o] = h;
    *(us4*)&dl[o] = l;
  }
}

// ---------------------------------------------------------------------------
// Pool + split: H (f32) -> Hh/Hl (bf16 split) and chunk-mean -> Hph/Hpl.
// Also zeroes route[] (4096 entries) for the screen's atomicMax.
// ---------------------------------------------------------------------------
__global__ __launch_bounds__(256) void pool_split_kernel(
    const float* __restrict__ H, ushort_t* __restrict__ Hh,
    ushort_t* __restrict__ Hl, ushort_t* __restrict__ Hph,
    ushort_t* __restrict__ Hpl, uint* __restrict__ route) {
  const int idx = blockIdx.x * 256 + threadIdx.x;  // < 4*1024*128
  if (idx < BATCH * NCHUNK) route[idx] = 0;
  const int e4 = (idx & 127) << 2;
  const int c = (idx >> 7) & 1023;
  const int b = idx >> 17;
  const size_t rbase = ((size_t)(b * SEQ + c * 4)) * 512 + e4;
  float4 s = make_float4(0.f, 0.f, 0.f, 0.f);
#pragma unroll
  for (int j = 0; j < 4; ++j) {
    float4 v = *(const float4*)&H[rbase + (size_t)j * 512];
    s.x += v.x; s.y += v.y; s.z += v.z; s.w += v.w;
    us4 h, l;
    float a[4] = {v.x, v.y, v.z, v.w};
#pragma unroll
    for (int q = 0; q < 4; ++q) {
      ushort_t hb = bf16_rn(a[q]);
      h[q] = hb;
      l[q] = bf16_rn(a[q] - bf16_f(hb));
    }
    *(us4*)&Hh[rbase + (size_t)j * 512] = h;
    *(us4*)&Hl[rbase + (size_t)j * 512] = l;
  }
  float a[4] = {s.x * 0.25f, s.y * 0.25f, s.z * 0.25f, s.w * 0.25f};
  us4 h, l;
#pragma unroll
  for (int q = 0; q < 4; ++q) {
    ushort_t hb = bf16_rn(a[q]);
    h[q] = hb;
    l[q] = bf16_rn(a[q] - bf16_f(hb));
  }
  size_t po = ((size_t)(b * NCHUNK + c)) * 512 + e4;
  *(us4*)&Hph[po] = h;
  *(us4*)&Hpl[po] = l;
}

// ---------------------------------------------------------------------------
// Merged projection GEMMs (Q full-seq + K|V pooled) in ONE launch.
// C(M,N) = A(M,512) @ Bt(N,512)^T, split-bf16 3 products. Tile 128x128,
// BK=32, dbuf LDS, global_load_lds(16B), XOR swizzle (<=2-way conflicts).
// Blocks 0..511: Q (16384x512); blocks 512..767: KV (4096x1024).
// ---------------------------------------------------------------------------
__global__ __launch_bounds__(256) void proj_kernel(
    const ushort_t* __restrict__ Hh, const ushort_t* __restrict__ Hl,
    const ushort_t* __restrict__ Hph, const ushort_t* __restrict__ Hpl,
    const ushort_t* __restrict__ Wtq_h, const ushort_t* __restrict__ Wtq_l,
    const ushort_t* __restrict__ Wtkv_h, const ushort_t* __restrict__ Wtkv_l,
    ushort_t* __restrict__ Qh, ushort_t* __restrict__ Ql,
    ushort_t* __restrict__ Pkvh, ushort_t* __restrict__ Pkvl) {
  __shared__ ushort_t lds[2][4][4096];  // [buf][Ah,Bh,Al,Bl][128*32]
  const int bid = blockIdx.x;
  const ushort_t *A0, *A1, *B0, *B1;
  ushort_t *Ch, *Cl;
  int ldc, row0, col0;
  if (bid < 512) {
    row0 = (bid >> 2) * 128; col0 = (bid & 3) * 128;
    A0 = Hh; A1 = Hl; B0 = Wtq_h; B1 = Wtq_l; Ch = Qh; Cl = Ql; ldc = 512;
  } else {
    int b2 = bid - 512;
    row0 = (b2 >> 3) * 128; col0 = (b2 & 7) * 128;
    A0 = Hph; A1 = Hpl; B0 = Wtkv_h; B1 = Wtkv_l; Ch = Pkvh; Cl = Pkvl;
    ldc = 1024;
  }
  A0 += (size_t)row0 * 512; A1 += (size_t)row0 * 512;
  B0 += (size_t)col0 * 512; B1 += (size_t)col0 * 512;
  const int tid = threadIdx.x, lane = tid & 63, wv = tid >> 6;
  const int l15 = lane & 15, g = lane >> 4;
  const int wm = wv >> 1, wn = wv & 1;
  f32x4 acc[4][4];
#pragma unroll
  for (int m = 0; m < 4; ++m)
#pragma unroll
    for (int n = 0; n < 4; ++n) acc[m][n] = (f32x4){0.f, 0.f, 0.f, 0.f};

  auto stage = [&](int buf, int t) {
#pragma unroll
    for (int j = 0; j < 2; ++j) {
      int si = j * 256 + wv * 64 + lane;
      int row = si >> 2;
      int kb = ((si & 3) << 4) ^ (((row >> 1) & 3) << 4);
      size_t goff = (size_t)row * 512 + t * 32 + (kb >> 1);
      int doff = (j * 256 + wv * 64) * 8;
      load_lds16(A0 + goff, &lds[buf][0][doff]);
      load_lds16(B0 + goff, &lds[buf][1][doff]);
      load_lds16(A1 + goff, &lds[buf][2][doff]);
      load_lds16(B1 + goff, &lds[buf][3][doff]);
    }
  };

  stage(0, 0);
  int cur = 0;
  for (int t = 0; t < 16; ++t) {
    __syncthreads();
    if (t < 15) stage(cur ^ 1, t + 1);
    short8 ah[4], bh[4], al[4], bl[4];
#pragma unroll
    for (int m = 0; m < 4; ++m) {
      int r = wm * 64 + m * 16 + l15;
      int kb = (g << 4) ^ (((r >> 1) & 3) << 4);
      ah[m] = *(const short8*)&lds[cur][0][r * 32 + (kb >> 1)];
      al[m] = *(const short8*)&lds[cur][2][r * 32 + (kb >> 1)];
    }
#pragma unroll
    for (int n = 0; n < 4; ++n) {
      int r = wn * 64 + n * 16 + l15;
      int kb = (g << 4) ^ (((r >> 1) & 3) << 4);
      bh[n] = *(const short8*)&lds[cur][1][r * 32 + (kb >> 1)];
      bl[n] = *(const short8*)&lds[cur][3][r * 32 + (kb >> 1)];
    }
#pragma unroll
    for (int m = 0; m < 4; ++m)
#pragma unroll
      for (int n = 0; n < 4; ++n) {
        acc[m][n] = mfma16(ah[m], bh[n], acc[m][n]);
        acc[m][n] = mfma16(ah[m], bl[n], acc[m][n]);
        acc[m][n] = mfma16(al[m], bh[n], acc[m][n]);
      }
    cur ^= 1;
  }
#pragma unroll
  for (int m = 0; m < 4; ++m)
#pragma unroll
    for (int n = 0; n < 4; ++n)
#pragma unroll
      for (int q = 0; q < 4; ++q) {
        int row = row0 + wm * 64 + m * 16 + g * 4 + q;
        int col = col0 + wn * 64 + n * 16 + l15;
        float v = acc[m][n][q];
        size_t o = (size_t)row * ldc + col;
        ushort_t hb = bf16_rn(v);
        Ch[o] = hb;
        Cl[o] = bf16_rn(v - bf16_f(hb));
      }
}

// ---------------------------------------------------------------------------
// Screen: per (b,h): S = Qh(4096x64) @ Pkh^T (bf16, 1 product), fused col-max
// epilogue -> atomicMax(route[b,c]). B-frags register-resident.
// ---------------------------------------------------------------------------
__device__ __forceinline__ void stage128x64(const ushort_t* src, int stride,
                                            ushort_t* dst, int wv, int lane) {
#pragma unroll
  for (int j = 0; j < 4; ++j) {
    int si = j * 256 + wv * 64 + lane;
    int row = si >> 3;
    int kb = ((si & 7) << 4) ^ ((row & 7) << 4);
    load_lds16(src + (size_t)row * stride + (kb >> 1),
               dst + (size_t)(j * 256 + wv * 64) * 8);
  }
}

__global__ __launch_bounds__(256) void route_screen(
    const ushort_t* __restrict__ Qh, const ushort_t* __restrict__ Pkh,
    uint* __restrict__ route) {
  __shared__ ushort_t Alds[2][128 * 64];
  __shared__ ushort_t Blds[128 * 64];
  __shared__ float red[2][128];
  const int tid = threadIdx.x, lane = tid & 63, wv = tid >> 6;
  const int l15 = lane & 15, g = lane >> 4;
  const int wm = wv >> 1, wc = wv & 1;
  const int c0 = blockIdx.x * 128;
  const int h = blockIdx.y >> 1, sb = blockIdx.y & 1;
  const int b = blockIdx.z;
  const int s0 = sb * 2048;
  const ushort_t* Qhb = Qh + ((size_t)b * SEQ) * 512 + h * 64;
  const ushort_t* Pkhb = Pkh + ((size_t)(b * NCHUNK + c0)) * 1024 + h * 64;

  stage128x64(Pkhb, 1024, &Blds[0], wv, lane);
  __syncthreads();
  short8 bh[2][4];
#pragma unroll
  for (int kk = 0; kk < 2; ++kk)
#pragma unroll
    for (int n = 0; n < 4; ++n) {
      int r = wc * 64 + n * 16 + l15;
      int kb = (kk * 64 + (g << 4)) ^ ((r & 7) << 4);
      bh[kk][n] = *(const short8*)&Blds[r * 64 + (kb >> 1)];
    }

  float rmax[4] = {-1e30f, -1e30f, -1e30f, -1e30f};
  stage128x64(Qhb + (size_t)s0 * 512, 512, &Alds[0][0], wv, lane);
  int cur = 0;
  for (int it = 0; it < 16; ++it) {
    __syncthreads();
    if (it < 15) {
      size_t so = (size_t)(s0 + (it + 1) * 128) * 512;
      stage128x64(Qhb + so, 512, &Alds[cur ^ 1][0], wv, lane);
    }
    f32x4 acc[4][4];
#pragma unroll
    for (int m = 0; m < 4; ++m)
#pragma unroll
      for (int n = 0; n < 4; ++n) acc[m][n] = (f32x4){0.f, 0.f, 0.f, 0.f};
#pragma unroll
    for (int kk = 0; kk < 2; ++kk) {
      short8 ah[4];
#pragma unroll
      for (int m = 0; m < 4; ++m) {
        int r = wm * 64 + m * 16 + l15;
        int kb = (kk * 64 + (g << 4)) ^ ((r & 7) << 4);
        ah[m] = *(const short8*)&Alds[cur][r * 64 + (kb >> 1)];
      }
#pragma unroll
      for (int m = 0; m < 4; ++m)
#pragma unroll
        for (int n = 0; n < 4; ++n)
          acc[m][n] = mfma16(ah[m], bh[kk][n], acc[m][n]);
    }
#pragma unroll
    for (int n = 0; n < 4; ++n)
#pragma unroll
      for (int m = 0; m < 4; ++m)
        rmax[n] = fmaxf(rmax[n],
                        fmaxf(fmaxf(acc[m][n][0], acc[m][n][1]),
                              fmaxf(acc[m][n][2], acc[m][n][3])));
    cur ^= 1;
  }
#pragma unroll
  for (int n = 0; n < 4; ++n) {
    float v = rmax[n];
    v = fmaxf(v, __shfl_xor(v, 16, 64));
    v = fmaxf(v, __shfl_xor(v, 32, 64));
    if (g == 0) red[wm][wc * 64 + n * 16 + l15] = v;
  }
  __syncthreads();
  if (tid < 128) {
    float v = fmaxf(red[0][tid], red[1][tid]);
    atomicMax(&route[b * NCHUNK + c0 + tid], float_key(v));
  }
}

// ---------------------------------------------------------------------------
// Top-NSEL via full bitonic sort of 1024 keys (55 barrier stages). Also
// zeroes route2 for the rescore's atomicMax. Same key packing as before.
// ---------------------------------------------------------------------------
__global__ __launch_bounds__(256) void topk_sel(const uint* __restrict__ route,
                                                int* __restrict__ cand,
                                                uint* __restrict__ route2) {
  const int b = blockIdx.x, tid = threadIdx.x;
  __shared__ unsigned long long keys[NCHUNK];
#pragma unroll
  for (int i = 0; i < 4; ++i) {
    int idx = tid + i * 256;
    keys[idx] = ((unsigned long long)route[b * NCHUNK + idx] << 32) |
                (uint)(NCHUNK - 1 - idx);  // tie -> lower index first
  }
  if (tid < NSEL) route2[b * NSEL + tid] = 0;
  __syncthreads();
  for (int k = 2; k <= NCHUNK; k <<= 1) {
    for (int j = k >> 1; j > 0; j >>= 1) {
#pragma unroll
      for (int ii = 0; ii < 4; ++ii) {
        int i = tid + ii * 256;
        int p = i ^ j;
        if (p > i) {
          bool desc = ((i & k) == 0);
          unsigned long long a = keys[i], c = keys[p];
          bool sw = desc ? (a < c) : (a > c);
          if (sw) { keys[i] = c; keys[p] = a; }
        }
      }
      __syncthreads();
    }
  }
  if (tid < NSEL)
    cand[b * NSEL + tid] = NCHUNK - 1 - (int)(keys[tid] & 0xffffffffu);
}

// ---------------------------------------------------------------------------
// Exact rescore of the 32 candidates: S = Q(128x64) @ Kc(32x64)^T per block,
// split-bf16 3 products. B gathered DIRECTLY from Pkv via cand (per-lane
// global source addresses). Fused col-max -> atomicMax(route2).
// ---------------------------------------------------------------------------
__global__ __launch_bounds__(256) void rescore_kernel(
    const ushort_t* __restrict__ Qh, const ushort_t* __restrict__ Ql,
    const ushort_t* __restrict__ Pkvh, const ushort_t* __restrict__ Pkvl,
    const int* __restrict__ cand, uint* __restrict__ route2) {
  __shared__ ushort_t Ah[128 * 64], Al[128 * 64];
  __shared__ ushort_t Bh[NSEL * 64], Bl[NSEL * 64];
  __shared__ float red[4][NSEL];
  const int tid = threadIdx.x, lane = tid & 63, wv = tid >> 6;
  const int l15 = lane & 15, g = lane >> 4;
  const int st = blockIdx.x, h = blockIdx.y, b = blockIdx.z;
  const int s0 = st * 128;
  // stage B (gathered): one 16B load per lane per array
  {
    int row = tid >> 3;
    int kb = ((tid & 7) << 4) ^ ((row & 7) << 4);
    int c = cand[b * NSEL + row];
    size_t src = ((size_t)(b * NCHUNK + c)) * 1024 + h * 64 + (kb >> 1);
    load_lds16(Pkvh + src, &Bh[(size_t)(wv * 64) * 8]);
    load_lds16(Pkvl + src, &Bl[(size_t)(wv * 64) * 8]);
  }
  // stage A (Q rows s0..s0+127, hi+lo)
  const ushort_t* Qhb = Qh + ((size_t)(b * SEQ + s0)) * 512 + h * 64;
  const ushort_t* Qlb = Ql + ((size_t)(b * SEQ + s0)) * 512 + h * 64;
  stage128x64(Qhb, 512, Ah, wv, lane);
  stage128x64(Qlb, 512, Al, wv, lane);
  __syncthreads();

  f32x4 acc[2][2];
#pragma unroll
  for (int m = 0; m < 2; ++m)
#pragma unroll
    for (int n = 0; n < 2; ++n) acc[m][n] = (f32x4){0.f, 0.f, 0.f, 0.f};
#pragma unroll
  for (int kk = 0; kk < 2; ++kk) {
    short8 ah[2], al[2], bh[2], bl[2];
#pragma unroll
    for (int m = 0; m < 2; ++m) {
      int r = wv * 32 + m * 16 + l15;
      int kb = (kk * 64 + (g << 4)) ^ ((r & 7) << 4);
      ah[m] = *(const short8*)&Ah[r * 64 + (kb >> 1)];
      al[m] = *(const short8*)&Al[r * 64 + (kb >> 1)];
    }
#pragma unroll
    for (int n = 0; n < 2; ++n) {
      int r = n * 16 + l15;
      int kb = (kk * 64 + (g << 4)) ^ ((r & 7) << 4);
      bh[n] = *(const short8*)&Bh[r * 64 + (kb >> 1)];
      bl[n] = *(const short8*)&Bl[r * 64 + (kb >> 1)];
    }
#pragma unroll
    for (int m = 0; m < 2; ++m)
#pragma unroll
      for (int n = 0; n < 2; ++n) {
        acc[m][n] = mfma16(ah[m], bh[n], acc[m][n]);
        acc[m][n] = mfma16(ah[m], bl[n], acc[m][n]);
        acc[m][n] = mfma16(al[m], bh[n], acc[m][n]);
      }
  }
#pragma unroll
  for (int n = 0; n < 2; ++n) {
    float v = -1e30f;
#pragma unroll
    for (int m = 0; m < 2; ++m)
      v = fmaxf(v, fmaxf(fmaxf(acc[m][n][0], acc[m][n][1]),
                         fmaxf(acc[m][n][2], acc[m][n][3])));
    v = fmaxf(v, __shfl_xor(v, 16, 64));
    v = fmaxf(v, __shfl_xor(v, 32, 64));
    if (g == 0) red[wv][n * 16 + l15] = v;
  }
  __syncthreads();
  if (tid < NSEL) {
    float v = fmaxf(fmaxf(red[0][tid], red[1][tid]),
                    fmaxf(red[2][tid], red[3][tid]));
    atomicMax(&route2[b * NSEL + tid], float_key(v));
  }
}

// ---------------------------------------------------------------------------
// Final top-8 among the 32 exactly-rescored candidates.
// ---------------------------------------------------------------------------
__global__ __launch_bounds__(64) void topk_final(const uint* __restrict__ route2,
                                                 const int* __restrict__ cand,
                                                 int* __restrict__ topidx) {
  const int b = blockIdx.x, lane = threadIdx.x;
  uint key = (lane < NSEL) ? route2[b * NSEL + lane] : 0u;
  const int myc = (lane < NSEL) ? cand[b * NSEL + lane] : 0;
  for (int it = 0; it < TOPK; ++it) {
    unsigned long long kk = ((unsigned long long)key << 32) | (uint)(63 - lane);
#pragma unroll
    for (int o = 32; o > 0; o >>= 1) {
      unsigned long long ot = __shfl_xor(kk, o, 64);
      kk = (ot > kk) ? ot : kk;
    }
    int widx = 63 - (int)(kk & 0xffffffffu);
    if (lane == widx) {
      topidx[b * TOPK + it] = myc;
      key = 0u;
    }
  }
}

// ---------------------------------------------------------------------------
// VW[b][hj][e] = sum_d V_sel[b,j,h,d]*Wo[h*64+d][e]; stored transposed
// VWt[b][e][hj] split hi/lo (linear) as the attn_out MFMA B-operand.
// ---------------------------------------------------------------------------
__global__ __launch_bounds__(256) void vw_kernel(
    const ushort_t* __restrict__ Pkvh, const ushort_t* __restrict__ Pkvl,
    const float* __restrict__ Wo, const int* __restrict__ topidx,
    ushort_t* __restrict__ VWth, ushort_t* __restrict__ VWtl) {
  __shared__ float Vs[8][512];
  const int tid = threadIdx.x, et = blockIdx.x, b = blockIdx.y;
#pragma unroll
  for (int i = 0; i < 16; ++i) {
    int idx = tid + i * 256;  // < 4096
    int j = idx >> 9, d = idx & 511;
    int c = topidx[b * TOPK + j];
    size_t src = ((size_t)(b * NCHUNK + c)) * 1024 + 512 + d;
    Vs[j][d] = bf16_f(Pkvh[src]) + bf16_f(Pkvl[src]);
  }
  __syncthreads();
  const int e = et * 64 + (tid & 63), qr = tid >> 6;
  ushort_t hbuf[16], lbuf[16];
#pragma unroll
  for (int i = 0; i < 16; ++i) {
    int hj = qr * 16 + i, h = hj >> 3, j = hj & 7;
    float dot = 0.f;
#pragma unroll
    for (int d = 0; d < 64; ++d)
      dot += Vs[j][h * 64 + d] * Wo[(size_t)(h * 64 + d) * 512 + e];
    ushort_t hb = bf16_rn(dot);
    hbuf[i] = hb;
    lbuf[i] = bf16_rn(dot - bf16_f(hb));
  }
  size_t o = ((size_t)(b * 512 + e)) * 64 + qr * 16;
  *(us8*)&VWth[o] = *(us8*)&hbuf[0];
  *(us8*)&VWth[o + 8] = *(us8*)&hbuf[8];
  *(us8*)&VWtl[o] = *(us8*)&lbuf[0];
  *(us8*)&VWtl[o + 8] = *(us8*)&lbuf[8];
}

// ---------------------------------------------------------------------------
// Fused attention epilogue: per 64-row s-tile, compute softmax weights P
// (f32 scores, split-bf16 into swizzled LDS), then out = P @ VW via MFMA
// (3 products, B-frags register-resident from global VWt). No P round-trip.
// ---------------------------------------------------------------------------
__global__ __launch_bounds__(256) void attn_out_kernel(
    const ushort_t* __restrict__ Qh, const ushort_t* __restrict__ Ql,
    const ushort_t* __restrict__ Pkvh, const ushort_t* __restrict__ Pkvl,
    const int* __restrict__ topidx, const ushort_t* __restrict__ VWth,
    const ushort_t* __restrict__ VWtl, float* __restrict__ out) {
  __shared__ float Ksel[8 * 516];           // [h*516 + j*64 + d], 516 kills bank conflicts
  __shared__ ushort_t Pho[64 * 64], Plo[64 * 64];  // swizzled, 8 KB each
  const int tid = threadIdx.x, lane = tid & 63, wv = tid >> 6;
  const int l15 = lane & 15, g = lane >> 4;
  const int st = blockIdx.x, b = blockIdx.y;
  const int s0 = st * 64;
  // ---- load K_sel (hi+lo -> f32)
  {
    int j = tid >> 5, h = (tid >> 2) & 7, dg = tid & 3;
    int c = topidx[b * TOPK + j];
    size_t base = ((size_t)(b * NCHUNK + c)) * 1024 + h * 64 + dg * 16;
    us8 h0 = *(const us8*)&Pkvh[base], h1 = *(const us8*)&Pkvh[base + 8];
    us8 l0 = *(const us8*)&Pkvl[base], l1 = *(const us8*)&Pkvl[base + 8];
#pragma unroll
    for (int ii = 0; ii < 8; ++ii) {
      Ksel[h * 516 + j * 64 + dg * 16 + ii] = bf16_f(h0[ii]) + bf16_f(l0[ii]);
      Ksel[h * 516 + j * 64 + dg * 16 + 8 + ii] = bf16_f(h1[ii]) + bf16_f(l1[ii]);
    }
  }
  __syncthreads();
  // ---- phase 1: P for rows s0..s0+63 (thread = (row, 2-head pair))
  {
    const int r = tid >> 2, hp = tid & 3;
    const size_t qbase = ((size_t)(b * SEQ + s0 + r)) * 512;
#pragma unroll
    for (int hh = 0; hh < 2; ++hh) {
      const int h = hp * 2 + hh;
      float qf[64];
#pragma unroll
      for (int i = 0; i < 8; ++i) {
        us8 vh = *(const us8*)&Qh[qbase + h * 64 + i * 8];
        us8 vl = *(const us8*)&Ql[qbase + h * 64 + i * 8];
#pragma unroll
        for (int k2 = 0; k2 < 8; ++k2)
          qf[i * 8 + k2] = bf16_f(vh[k2]) + bf16_f(vl[k2]);
      }
      float sc[TOPK], m = -1e30f;
#pragma unroll
      for (int j = 0; j < TOPK; ++j) {
        float dot = 0.f;
#pragma unroll
        for (int d4 = 0; d4 < 16; ++d4) {
          float4 kv = *(const float4*)&Ksel[h * 516 + j * 64 + d4 * 4];
          dot += qf[d4 * 4 + 0] * kv.x + qf[d4 * 4 + 1] * kv.y +
                 qf[d4 * 4 + 2] * kv.z + qf[d4 * 4 + 3] * kv.w;
        }
        sc[j] = dot * SCALING;
        m = fmaxf(m, sc[j]);
      }
      float se = 0.f, w8[TOPK];
#pragma unroll
      for (int j = 0; j < TOPK; ++j) {
        w8[j] = __expf(sc[j] - m);
        se += w8[j];
      }
      const float inv = 1.f / se;
      us8 ph8, pl8;
#pragma unroll
      for (int j = 0; j < TOPK; ++j) {
        float pv = w8[j] * inv;
        ushort_t hb = bf16_rn(pv);
        ph8[j] = hb;
        pl8[j] = bf16_rn(pv - bf16_f(hb));
      }
      int boff = (r * 128 + h * 16) ^ ((r & 7) << 4);
      *(us8*)((char*)Pho + boff) = ph8;
      *(us8*)((char*)Plo + boff) = pl8;
    }
  }
  __syncthreads();
  // ---- phase 2: out(64 x 512) = P(64x64) @ VW(64x512); wave -> 128 cols
  short8 pa[4][2], pb[4][2];
#pragma unroll
  for (int m = 0; m < 4; ++m) {
    int r = m * 16 + l15;
#pragma unroll
    for (int kk = 0; kk < 2; ++kk) {
      int boff = (r * 128 + kk * 64 + g * 16) ^ ((r & 7) << 4);
      pa[m][kk] = *(const short8*)((const char*)Pho + boff);
      pb[m][kk] = *(const short8*)((const char*)Plo + boff);
    }
  }
#pragma unroll
  for (int half = 0; half < 2; ++half) {
    const int colbase = wv * 128 + half * 64;
    short8 bh[4][2], bl[4][2];
#pragma unroll
    for (int n = 0; n < 4; ++n) {
      int e = colbase + n * 16 + l15;
      size_t vb = ((size_t)(b * 512 + e)) * 64;
#pragma unroll
      for (int kk = 0; kk < 2; ++kk) {
        bh[n][kk] = *(const short8*)&VWth[vb + kk * 32 + g * 8];
        bl[n][kk] = *(const short8*)&VWtl[vb + kk * 32 + g * 8];
      }
    }
    f32x4 acc[4][4];
#pragma unroll
    for (int m = 0; m < 4; ++m)
#pragma unroll
      for (int n = 0; n < 4; ++n) acc[m][n] = (f32x4){0.f, 0.f, 0.f, 0.f};
#pragma unroll
    for (int kk = 0; kk < 2; ++kk)
#pragma unroll
      for (int m = 0; m < 4; ++m)
#pragma unroll
        for (int n = 0; n < 4; ++n) {
          acc[m][n] = mfma16(pa[m][kk], bh[n][kk], acc[m][n]);
          acc[m][n] = mfma16(pa[m][kk], bl[n][kk], acc[m][n]);
          acc[m][n] = mfma16(pb[m][kk], bh[n][kk], acc[m][n]);
        }
#pragma unroll
    for (int m = 0; m < 4; ++m)
#pragma unroll
      for (int n = 0; n < 4; ++n)
#pragma unroll
        for (int q = 0; q < 4; ++q) {
          int row = s0 + m * 16 + g * 4 + q;
          int col = colbase + n * 16 + l15;
          out[((size_t)(b * SEQ) + row) * 512 + col] = acc[m][n][q];
        }
  }
}

// ---------------------------------------------------------------------------
extern "C" void kernel_launch(void* const* d_in, const int* in_sizes, int n_in,
                              void* d_out, int out_size, void* d_ws, size_t ws_size,
                              hipStream_t stream) {
  const float* H = (const float*)d_in[0];
  const float* Wq = (const float*)d_in[1];
  const float* Wk = (const float*)d_in[2];
  const float* Wv = (const float*)d_in[3];
  const float* Wo = (const float*)d_in[4];
  float* out = (float*)d_out;

  char* p = (char*)d_ws;
  auto alloc = [&](size_t bytes) {
    void* r = (void*)p;
    p += (bytes + 255) & ~(size_t)255;
    return r;
  };
  const size_t BS = (size_t)BATCH * SEQ;     // 16384
  const size_t BC = (size_t)BATCH * NCHUNK;  // 4096
  ushort_t* Hh = (ushort_t*)alloc(BS * 512 * 2);
  ushort_t* Hl = (ushort_t*)alloc(BS * 512 * 2);
  ushort_t* Hph = (ushort_t*)alloc(BC * 512 * 2);
  ushort_t* Hpl = (ushort_t*)alloc(BC * 512 * 2);
  ushort_t* Wtq_h = (ushort_t*)alloc(512 * 512 * 2);
  ushort_t* Wtq_l = (ushort_t*)alloc(512 * 512 * 2);
  ushort_t* Wtkv_h = (ushort_t*)alloc(1024 * 512 * 2);
  ushort_t* Wtkv_l = (ushort_t*)alloc(1024 * 512 * 2);
  ushort_t* Qh = (ushort_t*)alloc(BS * 512 * 2);
  ushort_t* Ql = (ushort_t*)alloc(BS * 512 * 2);
  ushort_t* Pkvh = (ushort_t*)alloc(BC * 1024 * 2);
  ushort_t* Pkvl = (ushort_t*)alloc(BC * 1024 * 2);
  ushort_t* VWth = (ushort_t*)alloc((size_t)BATCH * 512 * 64 * 2);
  ushort_t* VWtl = (ushort_t*)alloc((size_t)BATCH * 512 * 64 * 2);
  uint* route = (uint*)alloc(BC * 4);
  uint* route2 = (uint*)alloc((size_t)BATCH * NSEL * 4);
  int* cand = (int*)alloc(BATCH * NSEL * 4);
  int* topidx = (int*)alloc(BATCH * TOPK * 4);

  // 1. weight transpose/split; hidden pool/split (+route zero)
  wtrans_kernel<<<dim3(8, 8, 3), 256, 0, stream>>>(
      Wq, Wk, Wv, Wtq_h, Wtq_l, Wtkv_h, Wtkv_l);
  pool_split_kernel<<<2048, 256, 0, stream>>>(H, Hh, Hl, Hph, Hpl, route);
  // 2. merged projections (Q + KV) in one launch
  proj_kernel<<<768, 256, 0, stream>>>(Hh, Hl, Hph, Hpl, Wtq_h, Wtq_l,
                                       Wtkv_h, Wtkv_l, Qh, Ql, Pkvh, Pkvl);
  // 3. routing: bf16 screen -> bitonic top-32 -> gathered exact rescore -> top-8
  route_screen<<<dim3(8, 16, 4), 256, 0, stream>>>(Qh, Pkvh, route);
  topk_sel<<<BATCH, 256, 0, stream>>>(route, cand, route2);
  rescore_kernel<<<dim3(32, 8, 4), 256, 0, stream>>>(Qh, Ql, Pkvh, Pkvl, cand,
                                                     route2);
  topk_final<<<BATCH, 64, 0, stream>>>(route2, cand, topidx);
  // 4. VW = V_sel @ Wo (tiny), then fused P-softmax + (P @ VW) -> out
  vw_kernel<<<dim3(8, BATCH), 256, 0, stream>>>(Pkvh, Pkvl, Wo, topidx, VWth,
                                                VWtl);
  attn_out_kernel<<<dim3(64, BATCH), 256, 0, stream>>>(
      Qh, Ql, Pkvh, Pkvl, topidx, VWth, VWtl, out);
  (void)in_sizes; (void)n_in; (void)out_size; (void)ws_size;
}

// Round 5
// 239.383 us; speedup vs baseline: 4.4000x; 1.0725x over previous
//
#include <hip/hip_runtime.h>

#define SEQ 4096
#define BATCH 4
#define EMB 512
#define NHEAD 8
#define HDIM 64
#define NCHUNK 1024
#define TOPK 8
#define NSEL 32
#define SCALING 0.125f

typedef unsigned int uint;
typedef unsigned short ushort_t;
typedef __attribute__((ext_vector_type(8))) short short8;
typedef __attribute__((ext_vector_type(4))) float f32x4;
typedef __attribute__((ext_vector_type(4))) unsigned short us4;
typedef __attribute__((ext_vector_type(8))) unsigned short us8;

// ---- bf16 split helpers (x ~= hi + lo, each bf16; RNE rounding) -----------
__device__ __forceinline__ ushort_t bf16_rn(float x) {
  uint b = __float_as_uint(x);
  return (ushort_t)((b + 0x7FFFu + ((b >> 16) & 1u)) >> 16);
}
__device__ __forceinline__ float bf16_f(ushort_t u) {
  return __uint_as_float(((uint)u) << 16);
}

// ---- async global->LDS, 16B per lane (dst = wave base + lane*16) ----------
__device__ __forceinline__ void load_lds16(const void* g, void* l) {
  __builtin_amdgcn_global_load_lds(
      (const __attribute__((address_space(1))) unsigned int*)g,
      (__attribute__((address_space(3))) unsigned int*)l, 16, 0, 0);
}

__device__ __forceinline__ f32x4 mfma16(short8 a, short8 b, f32x4 c) {
  return __builtin_amdgcn_mfma_f32_16x16x32_bf16(a, b, c, 0, 0, 0);
}

__device__ __forceinline__ uint float_key(float f) {
  uint bits = __float_as_uint(f);
  return (bits & 0x80000000u) ? ~bits : (bits | 0x80000000u);
}

// ---- deterministic top-8 of the 32 rescored candidates (one wave) ---------
__device__ __forceinline__ void top8_inline(const uint* __restrict__ route2,
                                            const int* __restrict__ cand,
                                            int b, int lane,
                                            int* __restrict__ tops) {
  uint key = (lane < NSEL) ? route2[b * NSEL + lane] : 0u;
  const int myc = (lane < NSEL) ? cand[b * NSEL + lane] : 0;
  for (int it = 0; it < TOPK; ++it) {
    unsigned long long kk = ((unsigned long long)key << 32) | (uint)(63 - lane);
#pragma unroll
    for (int o = 32; o > 0; o >>= 1) {
      unsigned long long ot = __shfl_xor(kk, o, 64);
      kk = (ot > kk) ? ot : kk;
    }
    int widx = 63 - (int)(kk & 0xffffffffu);
    if (lane == widx) {
      tops[it] = myc;
      key = 0u;
    }
  }
}

// ---------------------------------------------------------------------------
// Prep (merged): blocks 0..2047 = pool+split of H (+ route zero);
// blocks 2048..2239 = weight transpose+split (Wq, Wk, Wv).
// ---------------------------------------------------------------------------
__global__ __launch_bounds__(256) void prep_kernel(
    const float* __restrict__ H, const float* __restrict__ Wq,
    const float* __restrict__ Wk, const float* __restrict__ Wv,
    ushort_t* __restrict__ Hh, ushort_t* __restrict__ Hl,
    ushort_t* __restrict__ Hph, ushort_t* __restrict__ Hpl,
    ushort_t* __restrict__ Wtq_h, ushort_t* __restrict__ Wtq_l,
    ushort_t* __restrict__ Wtkv_h, ushort_t* __restrict__ Wtkv_l,
    uint* __restrict__ route) {
  __shared__ float t[64][65];
  const int tid = threadIdx.x;
  if (blockIdx.x < 2048) {
    const int idx = blockIdx.x * 256 + tid;  // < 4*1024*128
    if (idx < BATCH * NCHUNK) route[idx] = 0;
    const int e4 = (idx & 127) << 2;
    const int c = (idx >> 7) & 1023;
    const int b = idx >> 17;
    const size_t rbase = ((size_t)(b * SEQ + c * 4)) * 512 + e4;
    float4 s = make_float4(0.f, 0.f, 0.f, 0.f);
#pragma unroll
    for (int j = 0; j < 4; ++j) {
      float4 v = *(const float4*)&H[rbase + (size_t)j * 512];
      s.x += v.x; s.y += v.y; s.z += v.z; s.w += v.w;
      us4 h, l;
      float a[4] = {v.x, v.y, v.z, v.w};
#pragma unroll
      for (int q = 0; q < 4; ++q) {
        ushort_t hb = bf16_rn(a[q]);
        h[q] = hb;
        l[q] = bf16_rn(a[q] - bf16_f(hb));
      }
      *(us4*)&Hh[rbase + (size_t)j * 512] = h;
      *(us4*)&Hl[rbase + (size_t)j * 512] = l;
    }
    float a[4] = {s.x * 0.25f, s.y * 0.25f, s.z * 0.25f, s.w * 0.25f};
    us4 h, l;
#pragma unroll
    for (int q = 0; q < 4; ++q) {
      ushort_t hb = bf16_rn(a[q]);
      h[q] = hb;
      l[q] = bf16_rn(a[q] - bf16_f(hb));
    }
    size_t po = ((size_t)(b * NCHUNK + c)) * 512 + e4;
    *(us4*)&Hph[po] = h;
    *(us4*)&Hpl[po] = l;
  } else {
    const int bid2 = blockIdx.x - 2048;  // 0..191
    const int z = bid2 >> 6;             // matrix
    const int xy = bid2 & 63;
    const int k0 = (xy & 7) * 64, n0 = (xy >> 3) * 64;
    const float* src = (z == 0) ? Wq : (z == 1) ? Wk : Wv;
    ushort_t* dh = (z == 0) ? Wtq_h : Wtkv_h;
    ushort_t* dl = (z == 0) ? Wtq_l : Wtkv_l;
    const size_t obase = (z == 2) ? (size_t)512 * 512 : 0;  // Wv rows 512+
#pragma unroll
    for (int i = 0; i < 4; ++i) {
      int row = (tid >> 4) + i * 16, col = (tid & 15) * 4;
      float4 v = *(const float4*)&src[(size_t)(k0 + row) * 512 + n0 + col];
      t[row][col + 0] = v.x; t[row][col + 1] = v.y;
      t[row][col + 2] = v.z; t[row][col + 3] = v.w;
    }
    __syncthreads();
#pragma unroll
    for (int i = 0; i < 4; ++i) {
      int nrow = (tid >> 4) + i * 16, kcol = (tid & 15) * 4;
      us4 h, l;
#pragma unroll
      for (int j = 0; j < 4; ++j) {
        float v = t[kcol + j][nrow];
        ushort_t hb = bf16_rn(v);
        h[j] = hb;
        l[j] = bf16_rn(v - bf16_f(hb));
      }
      size_t o = obase + (size_t)(n0 + nrow) * 512 + k0 + kcol;
      *(us4*)&dh[o] = h;
      *(us4*)&dl[o] = l;
    }
  }
}

// ---------------------------------------------------------------------------
// Merged projection GEMMs (Q full-seq + K|V pooled), split-bf16 3 products.
// Tile 128x128, BK=32, SINGLE-buffer LDS (32 KB -> 4-5 blocks/CU, no grid
// tail), global_load_lds(16B), XOR swizzle. XCD-aware block remap: all
// col-blocks of one A row-panel share blockIdx%8 -> same XCD L2.
// ---------------------------------------------------------------------------
__global__ __launch_bounds__(256) void proj_kernel(
    const ushort_t* __restrict__ Hh, const ushort_t* __restrict__ Hl,
    const ushort_t* __restrict__ Hph, const ushort_t* __restrict__ Hpl,
    const ushort_t* __restrict__ Wtq_h, const ushort_t* __restrict__ Wtq_l,
    const ushort_t* __restrict__ Wtkv_h, const ushort_t* __restrict__ Wtkv_l,
    ushort_t* __restrict__ Qh, ushort_t* __restrict__ Ql,
    ushort_t* __restrict__ Pkvh, ushort_t* __restrict__ Pkvl) {
  __shared__ ushort_t lds[4][4096];  // [Ah,Bh,Al,Bl][128*32], 32 KB
  const int bid = blockIdx.x;
  const ushort_t *A0, *A1, *B0, *B1;
  ushort_t *Ch, *Cl;
  int ldc, row0, col0;
  if (bid < 512) {  // Q: 128 row-panels x 4 col-blocks
    int xcd = bid & 7, idx = bid >> 3;
    int r = (idx >> 2) * 8 + xcd, c = idx & 3;
    row0 = r * 128; col0 = c * 128;
    A0 = Hh; A1 = Hl; B0 = Wtq_h; B1 = Wtq_l; Ch = Qh; Cl = Ql; ldc = 512;
  } else {  // KV: 32 row-panels x 8 col-blocks
    int b2 = bid - 512;
    int xcd = b2 & 7, idx = b2 >> 3;
    int r = (idx >> 3) * 8 + xcd, c = idx & 7;
    row0 = r * 128; col0 = c * 128;
    A0 = Hph; A1 = Hpl; B0 = Wtkv_h; B1 = Wtkv_l; Ch = Pkvh; Cl = Pkvl;
    ldc = 1024;
  }
  A0 += (size_t)row0 * 512; A1 += (size_t)row0 * 512;
  B0 += (size_t)col0 * 512; B1 += (size_t)col0 * 512;
  const int tid = threadIdx.x, lane = tid & 63, wv = tid >> 6;
  const int l15 = lane & 15, g = lane >> 4;
  const int wm = wv >> 1, wn = wv & 1;
  f32x4 acc[4][4];
#pragma unroll
  for (int m = 0; m < 4; ++m)
#pragma unroll
    for (int n = 0; n < 4; ++n) acc[m][n] = (f32x4){0.f, 0.f, 0.f, 0.f};

  auto stage = [&](int t) {
#pragma unroll
    for (int j = 0; j < 2; ++j) {
      int si = j * 256 + wv * 64 + lane;
      int row = si >> 2;
      int kb = ((si & 3) << 4) ^ (((row >> 1) & 3) << 4);
      size_t goff = (size_t)row * 512 + t * 32 + (kb >> 1);
      int doff = (j * 256 + wv * 64) * 8;
      load_lds16(A0 + goff, &lds[0][doff]);
      load_lds16(B0 + goff, &lds[1][doff]);
      load_lds16(A1 + goff, &lds[2][doff]);
      load_lds16(B1 + goff, &lds[3][doff]);
    }
  };

  stage(0);
  for (int t = 0; t < 16; ++t) {
    __syncthreads();  // drains vmcnt -> staged tile visible
    short8 ah[4], bh[4], al[4], bl[4];
#pragma unroll
    for (int m = 0; m < 4; ++m) {
      int r = wm * 64 + m * 16 + l15;
      int kb = (g << 4) ^ (((r >> 1) & 3) << 4);
      ah[m] = *(const short8*)&lds[0][r * 32 + (kb >> 1)];
      al[m] = *(const short8*)&lds[2][r * 32 + (kb >> 1)];
    }
#pragma unroll
    for (int n = 0; n < 4; ++n) {
      int r = wn * 64 + n * 16 + l15;
      int kb = (g << 4) ^ (((r >> 1) & 3) << 4);
      bh[n] = *(const short8*)&lds[1][r * 32 + (kb >> 1)];
      bl[n] = *(const short8*)&lds[3][r * 32 + (kb >> 1)];
    }
#pragma unroll
    for (int m = 0; m < 4; ++m)
#pragma unroll
      for (int n = 0; n < 4; ++n) {
        acc[m][n] = mfma16(ah[m], bh[n], acc[m][n]);
        acc[m][n] = mfma16(ah[m], bl[n], acc[m][n]);
        acc[m][n] = mfma16(al[m], bh[n], acc[m][n]);
      }
    __syncthreads();  // all reads done before overwrite
    if (t < 15) stage(t + 1);
  }
#pragma unroll
  for (int m = 0; m < 4; ++m)
#pragma unroll
    for (int n = 0; n < 4; ++n)
#pragma unroll
      for (int q = 0; q < 4; ++q) {
        int row = row0 + wm * 64 + m * 16 + g * 4 + q;
        int col = col0 + wn * 64 + n * 16 + l15;
        float v = acc[m][n][q];
        size_t o = (size_t)row * ldc + col;
        ushort_t hb = bf16_rn(v);
        Ch[o] = hb;
        Cl[o] = bf16_rn(v - bf16_f(hb));
      }
}

// ---------------------------------------------------------------------------
// Screen: per (b,h): S = Qh(4096x64) @ Pkh^T (bf16, 1 product), fused col-max
// -> atomicMax(route). Single A-buffer; XCD remap: the 8 c0-blocks of one
// (b,h,s-half) group share blockIdx%8 (Q slice fetched once per XCD).
// ---------------------------------------------------------------------------
__device__ __forceinline__ void stage128x64(const ushort_t* src, int stride,
                                            ushort_t* dst, int wv, int lane) {
#pragma unroll
  for (int j = 0; j < 4; ++j) {
    int si = j * 256 + wv * 64 + lane;
    int row = si >> 3;
    int kb = ((si & 7) << 4) ^ ((row & 7) << 4);
    load_lds16(src + (size_t)row * stride + (kb >> 1),
               dst + (size_t)(j * 256 + wv * 64) * 8);
  }
}

__global__ __launch_bounds__(256) void route_screen(
    const ushort_t* __restrict__ Qh, const ushort_t* __restrict__ Pkh,
    uint* __restrict__ route) {
  __shared__ ushort_t Alds[128 * 64];  // 16 KB
  __shared__ ushort_t Blds[128 * 64];  // 16 KB
  __shared__ float red[2][128];
  const int tid = threadIdx.x, lane = tid & 63, wv = tid >> 6;
  const int l15 = lane & 15, g = lane >> 4;
  const int wm = wv >> 1, wc = wv & 1;
  const int bid = blockIdx.x;  // 512 blocks
  const int gl = bid & 7, c0i = (bid >> 3) & 7, gh = bid >> 6;
  const int grp = gh * 8 + gl;  // (b,h,sb), its 8 c0-blocks share bid%8
  const int b = grp >> 4, h = (grp >> 1) & 7, sb = grp & 1;
  const int c0 = c0i * 128;
  const int s0 = sb * 2048;
  const ushort_t* Qhb = Qh + ((size_t)b * SEQ) * 512 + h * 64;
  const ushort_t* Pkhb = Pkh + ((size_t)(b * NCHUNK + c0)) * 1024 + h * 64;

  stage128x64(Pkhb, 1024, &Blds[0], wv, lane);
  stage128x64(Qhb + (size_t)s0 * 512, 512, &Alds[0], wv, lane);
  __syncthreads();  // drains B + A(0)
  short8 bh[2][4];
#pragma unroll
  for (int kk = 0; kk < 2; ++kk)
#pragma unroll
    for (int n = 0; n < 4; ++n) {
      int r = wc * 64 + n * 16 + l15;
      int kb = (kk * 64 + (g << 4)) ^ ((r & 7) << 4);
      bh[kk][n] = *(const short8*)&Blds[r * 64 + (kb >> 1)];
    }

  float rmax[4] = {-1e30f, -1e30f, -1e30f, -1e30f};
  for (int it = 0; it < 16; ++it) {
    f32x4 acc[4][4];
#pragma unroll
    for (int m = 0; m < 4; ++m)
#pragma unroll
      for (int n = 0; n < 4; ++n) acc[m][n] = (f32x4){0.f, 0.f, 0.f, 0.f};
#pragma unroll
    for (int kk = 0; kk < 2; ++kk) {
      short8 ah[4];
#pragma unroll
      for (int m = 0; m < 4; ++m) {
        int r = wm * 64 + m * 16 + l15;
        int kb = (kk * 64 + (g << 4)) ^ ((r & 7) << 4);
        ah[m] = *(const short8*)&Alds[r * 64 + (kb >> 1)];
      }
#pragma unroll
      for (int m = 0; m < 4; ++m)
#pragma unroll
        for (int n = 0; n < 4; ++n)
          acc[m][n] = mfma16(ah[m], bh[kk][n], acc[m][n]);
    }
#pragma unroll
    for (int n = 0; n < 4; ++n)
#pragma unroll
      for (int m = 0; m < 4; ++m)
        rmax[n] = fmaxf(rmax[n],
                        fmaxf(fmaxf(acc[m][n][0], acc[m][n][1]),
                              fmaxf(acc[m][n][2], acc[m][n][3])));
    __syncthreads();  // readers done
    if (it < 15) {
      size_t so = (size_t)(s0 + (it + 1) * 128) * 512;
      stage128x64(Qhb + so, 512, &Alds[0], wv, lane);
    }
    __syncthreads();  // drain vmcnt -> next tile visible
  }
#pragma unroll
  for (int n = 0; n < 4; ++n) {
    float v = rmax[n];
    v = fmaxf(v, __shfl_xor(v, 16, 64));
    v = fmaxf(v, __shfl_xor(v, 32, 64));
    if (g == 0) red[wm][wc * 64 + n * 16 + l15] = v;
  }
  __syncthreads();
  if (tid < 128) {
    float v = fmaxf(red[0][tid], red[1][tid]);
    atomicMax(&route[b * NCHUNK + c0 + tid], float_key(v));
  }
}

// ---------------------------------------------------------------------------
// Top-NSEL via bitonic sort of 1024 keys; zeroes route2 for the rescore.
// ---------------------------------------------------------------------------
__global__ __launch_bounds__(256) void topk_sel(const uint* __restrict__ route,
                                                int* __restrict__ cand,
                                                uint* __restrict__ route2) {
  const int b = blockIdx.x, tid = threadIdx.x;
  __shared__ unsigned long long keys[NCHUNK];
#pragma unroll
  for (int i = 0; i < 4; ++i) {
    int idx = tid + i * 256;
    keys[idx] = ((unsigned long long)route[b * NCHUNK + idx] << 32) |
                (uint)(NCHUNK - 1 - idx);  // tie -> lower index first
  }
  if (tid < NSEL) route2[b * NSEL + tid] = 0;
  __syncthreads();
  for (int k = 2; k <= NCHUNK; k <<= 1) {
    for (int j = k >> 1; j > 0; j >>= 1) {
#pragma unroll
      for (int ii = 0; ii < 4; ++ii) {
        int i = tid + ii * 256;
        int p = i ^ j;
        if (p > i) {
          bool desc = ((i & k) == 0);
          unsigned long long a = keys[i], c = keys[p];
          bool sw = desc ? (a < c) : (a > c);
          if (sw) { keys[i] = c; keys[p] = a; }
        }
      }
      __syncthreads();
    }
  }
  if (tid < NSEL)
    cand[b * NSEL + tid] = NCHUNK - 1 - (int)(keys[tid] & 0xffffffffu);
}

// ---------------------------------------------------------------------------
// Exact rescore of the 32 candidates: split-bf16 3 products, B gathered
// directly from Pkv via cand. Fused col-max -> atomicMax(route2).
// ---------------------------------------------------------------------------
__global__ __launch_bounds__(256) void rescore_kernel(
    const ushort_t* __restrict__ Qh, const ushort_t* __restrict__ Ql,
    const ushort_t* __restrict__ Pkvh, const ushort_t* __restrict__ Pkvl,
    const int* __restrict__ cand, uint* __restrict__ route2) {
  __shared__ ushort_t Ah[128 * 64], Al[128 * 64];
  __shared__ ushort_t Bh[NSEL * 64], Bl[NSEL * 64];
  __shared__ float red[4][NSEL];
  const int tid = threadIdx.x, lane = tid & 63, wv = tid >> 6;
  const int l15 = lane & 15, g = lane >> 4;
  const int st = blockIdx.x, h = blockIdx.y, b = blockIdx.z;
  const int s0 = st * 128;
  {
    int row = tid >> 3;
    int kb = ((tid & 7) << 4) ^ ((row & 7) << 4);
    int c = cand[b * NSEL + row];
    size_t src = ((size_t)(b * NCHUNK + c)) * 1024 + h * 64 + (kb >> 1);
    load_lds16(Pkvh + src, &Bh[(size_t)(wv * 64) * 8]);
    load_lds16(Pkvl + src, &Bl[(size_t)(wv * 64) * 8]);
  }
  const ushort_t* Qhb = Qh + ((size_t)(b * SEQ + s0)) * 512 + h * 64;
  const ushort_t* Qlb = Ql + ((size_t)(b * SEQ + s0)) * 512 + h * 64;
  stage128x64(Qhb, 512, Ah, wv, lane);
  stage128x64(Qlb, 512, Al, wv, lane);
  __syncthreads();

  f32x4 acc[2][2];
#pragma unroll
  for (int m = 0; m < 2; ++m)
#pragma unroll
    for (int n = 0; n < 2; ++n) acc[m][n] = (f32x4){0.f, 0.f, 0.f, 0.f};
#pragma unroll
  for (int kk = 0; kk < 2; ++kk) {
    short8 ah[2], al[2], bh[2], bl[2];
#pragma unroll
    for (int m = 0; m < 2; ++m) {
      int r = wv * 32 + m * 16 + l15;
      int kb = (kk * 64 + (g << 4)) ^ ((r & 7) << 4);
      ah[m] = *(const short8*)&Ah[r * 64 + (kb >> 1)];
      al[m] = *(const short8*)&Al[r * 64 + (kb >> 1)];
    }
#pragma unroll
    for (int n = 0; n < 2; ++n) {
      int r = n * 16 + l15;
      int kb = (kk * 64 + (g << 4)) ^ ((r & 7) << 4);
      bh[n] = *(const short8*)&Bh[r * 64 + (kb >> 1)];
      bl[n] = *(const short8*)&Bl[r * 64 + (kb >> 1)];
    }
#pragma unroll
    for (int m = 0; m < 2; ++m)
#pragma unroll
      for (int n = 0; n < 2; ++n) {
        acc[m][n] = mfma16(ah[m], bh[n], acc[m][n]);
        acc[m][n] = mfma16(ah[m], bl[n], acc[m][n]);
        acc[m][n] = mfma16(al[m], bh[n], acc[m][n]);
      }
  }
#pragma unroll
  for (int n = 0; n < 2; ++n) {
    float v = -1e30f;
#pragma unroll
    for (int m = 0; m < 2; ++m)
      v = fmaxf(v, fmaxf(fmaxf(acc[m][n][0], acc[m][n][1]),
                         fmaxf(acc[m][n][2], acc[m][n][3])));
    v = fmaxf(v, __shfl_xor(v, 16, 64));
    v = fmaxf(v, __shfl_xor(v, 32, 64));
    if (g == 0) red[wv][n * 16 + l15] = v;
  }
  __syncthreads();
  if (tid < NSEL) {
    float v = fmaxf(fmaxf(red[0][tid], red[1][tid]),
                    fmaxf(red[2][tid], red[3][tid]));
    atomicMax(&route2[b * NSEL + tid], float_key(v));
  }
}

// ---------------------------------------------------------------------------
// VW[b][hj][e] = sum_d V_sel[b,j,h,d]*Wo[h*64+d][e]; transposed split output.
// Top-8 recomputed inline (deterministic) -> no topidx dependency kernel.
// ---------------------------------------------------------------------------
__global__ __launch_bounds__(256) void vw_kernel(
    const ushort_t* __restrict__ Pkvh, const ushort_t* __restrict__ Pkvl,
    const float* __restrict__ Wo, const uint* __restrict__ route2,
    const int* __restrict__ cand, ushort_t* __restrict__ VWth,
    ushort_t* __restrict__ VWtl) {
  __shared__ float Vs[8][512];
  __shared__ int tops[TOPK];
  const int tid = threadIdx.x, et = blockIdx.x, b = blockIdx.y;
  if (tid < 64) top8_inline(route2, cand, b, tid, tops);
  __syncthreads();
#pragma unroll
  for (int i = 0; i < 16; ++i) {
    int idx = tid + i * 256;  // < 4096
    int j = idx >> 9, d = idx & 511;
    int c = tops[j];
    size_t src = ((size_t)(b * NCHUNK + c)) * 1024 + 512 + d;
    Vs[j][d] = bf16_f(Pkvh[src]) + bf16_f(Pkvl[src]);
  }
  __syncthreads();
  const int e = et * 64 + (tid & 63), qr = tid >> 6;
  ushort_t hbuf[16], lbuf[16];
#pragma unroll
  for (int i = 0; i < 16; ++i) {
    int hj = qr * 16 + i, h = hj >> 3, j = hj & 7;
    float dot = 0.f;
#pragma unroll
    for (int d = 0; d < 64; ++d)
      dot += Vs[j][h * 64 + d] * Wo[(size_t)(h * 64 + d) * 512 + e];
    ushort_t hb = bf16_rn(dot);
    hbuf[i] = hb;
    lbuf[i] = bf16_rn(dot - bf16_f(hb));
  }
  size_t o = ((size_t)(b * 512 + e)) * 64 + qr * 16;
  *(us8*)&VWth[o] = *(us8*)&hbuf[0];
  *(us8*)&VWth[o + 8] = *(us8*)&hbuf[8];
  *(us8*)&VWtl[o] = *(us8*)&lbuf[0];
  *(us8*)&VWtl[o + 8] = *(us8*)&lbuf[8];
}

// ---------------------------------------------------------------------------
// Fused attention epilogue: top-8 inline, softmax weights P (Qh-only scores,
// split-bf16 into swizzled LDS), then out = P @ VW via MFMA (3 products).
// ---------------------------------------------------------------------------
__global__ __launch_bounds__(256) void attn_out_kernel(
    const ushort_t* __restrict__ Qh, const ushort_t* __restrict__ Pkvh,
    const ushort_t* __restrict__ Pkvl, const uint* __restrict__ route2,
    const int* __restrict__ cand, const ushort_t* __restrict__ VWth,
    const ushort_t* __restrict__ VWtl, float* __restrict__ out) {
  __shared__ float Ksel[8 * 516];  // [h*516 + j*64 + d]
  __shared__ ushort_t Pho[64 * 64], Plo[64 * 64];  // swizzled
  __shared__ int tops[TOPK];
  const int tid = threadIdx.x, lane = tid & 63, wv = tid >> 6;
  const int l15 = lane & 15, g = lane >> 4;
  const int st = blockIdx.x, b = blockIdx.y;
  const int s0 = st * 64;
  if (tid < 64) top8_inline(route2, cand, b, tid, tops);
  __syncthreads();
  // ---- load K_sel (hi+lo -> f32)
  {
    int j = tid >> 5, h = (tid >> 2) & 7, dg = tid & 3;
    int c = tops[j];
    size_t base = ((size_t)(b * NCHUNK + c)) * 1024 + h * 64 + dg * 16;
    us8 h0 = *(const us8*)&Pkvh[base], h1 = *(const us8*)&Pkvh[base + 8];
    us8 l0 = *(const us8*)&Pkvl[base], l1 = *(const us8*)&Pkvl[base + 8];
#pragma unroll
    for (int ii = 0; ii < 8; ++ii) {
      Ksel[h * 516 + j * 64 + dg * 16 + ii] = bf16_f(h0[ii]) + bf16_f(l0[ii]);
      Ksel[h * 516 + j * 64 + dg * 16 + 8 + ii] =
          bf16_f(h1[ii]) + bf16_f(l1[ii]);
    }
  }
  __syncthreads();
  // ---- phase 1: P rows s0..s0+63 (thread = (row, 2-head pair)); Qh only
  {
    const int r = tid >> 2, hp = tid & 3;
    const size_t qbase = ((size_t)(b * SEQ + s0 + r)) * 512;
#pragma unroll
    for (int hh = 0; hh < 2; ++hh) {
      const int h = hp * 2 + hh;
      float qf[64];
#pragma unroll
      for (int i = 0; i < 8; ++i) {
        us8 vh = *(const us8*)&Qh[qbase + h * 64 + i * 8];
#pragma unroll
        for (int k2 = 0; k2 < 8; ++k2) qf[i * 8 + k2] = bf16_f(vh[k2]);
      }
      float sc[TOPK], m = -1e30f;
#pragma unroll
      for (int j = 0; j < TOPK; ++j) {
        float dot = 0.f;
#pragma unroll
        for (int d4 = 0; d4 < 16; ++d4) {
          float4 kv = *(const float4*)&Ksel[h * 516 + j * 64 + d4 * 4];
          dot += qf[d4 * 4 + 0] * kv.x + qf[d4 * 4 + 1] * kv.y +
                 qf[d4 * 4 + 2] * kv.z + qf[d4 * 4 + 3] * kv.w;
        }
        sc[j] = dot * SCALING;
        m = fmaxf(m, sc[j]);
      }
      float se = 0.f, w8[TOPK];
#pragma unroll
      for (int j = 0; j < TOPK; ++j) {
        w8[j] = __expf(sc[j] - m);
        se += w8[j];
      }
      const float inv = 1.f / se;
      us8 ph8, pl8;
#pragma unroll
      for (int j = 0; j < TOPK; ++j) {
        float pv = w8[j] * inv;
        ushort_t hb = bf16_rn(pv);
        ph8[j] = hb;
        pl8[j] = bf16_rn(pv - bf16_f(hb));
      }
      int boff = (r * 128 + h * 16) ^ ((r & 7) << 4);
      *(us8*)((char*)Pho + boff) = ph8;
      *(us8*)((char*)Plo + boff) = pl8;
    }
  }
  __syncthreads();
  // ---- phase 2: out(64 x 512) = P(64x64) @ VW(64x512); wave -> 128 cols
  short8 pa[4][2], pb[4][2];
#pragma unroll
  for (int m = 0; m < 4; ++m) {
    int r = m * 16 + l15;
#pragma unroll
    for (int kk = 0; kk < 2; ++kk) {
      int boff = (r * 128 + kk * 64 + g * 16) ^ ((r & 7) << 4);
      pa[m][kk] = *(const short8*)((const char*)Pho + boff);
      pb[m][kk] = *(const short8*)((const char*)Plo + boff);
    }
  }
#pragma unroll
  for (int half = 0; half < 2; ++half) {
    const int colbase = wv * 128 + half * 64;
    short8 bh[4][2], bl[4][2];
#pragma unroll
    for (int n = 0; n < 4; ++n) {
      int e = colbase + n * 16 + l15;
      size_t vb = ((size_t)(b * 512 + e)) * 64;
#pragma unroll
      for (int kk = 0; kk < 2; ++kk) {
        bh[n][kk] = *(const short8*)&VWth[vb + kk * 32 + g * 8];
        bl[n][kk] = *(const short8*)&VWtl[vb + kk * 32 + g * 8];
      }
    }
    f32x4 acc[4][4];
#pragma unroll
    for (int m = 0; m < 4; ++m)
#pragma unroll
      for (int n = 0; n < 4; ++n) acc[m][n] = (f32x4){0.f, 0.f, 0.f, 0.f};
#pragma unroll
    for (int kk = 0; kk < 2; ++kk)
#pragma unroll
      for (int m = 0; m < 4; ++m)
#pragma unroll
        for (int n = 0; n < 4; ++n) {
          acc[m][n] = mfma16(pa[m][kk], bh[n][kk], acc[m][n]);
          acc[m][n] = mfma16(pa[m][kk], bl[n][kk], acc[m][n]);
          acc[m][n] = mfma16(pb[m][kk], bh[n][kk], acc[m][n]);
        }
#pragma unroll
    for (int m = 0; m < 4; ++m)
#pragma unroll
      for (int n = 0; n < 4; ++n)
#pragma unroll
        for (int q = 0; q < 4; ++q) {
          int row = s0 + m * 16 + g * 4 + q;
          int col = colbase + n * 16 + l15;
          out[((size_t)(b * SEQ) + row) * 512 + col] = acc[m][n][q];
        }
  }
}

// ---------------------------------------------------------------------------
extern "C" void kernel_launch(void* const* d_in, const int* in_sizes, int n_in,
                              void* d_out, int out_size, void* d_ws, size_t ws_size,
                              hipStream_t stream) {
  const float* H = (const float*)d_in[0];
  const float* Wq = (const float*)d_in[1];
  const float* Wk = (const float*)d_in[2];
  const float* Wv = (const float*)d_in[3];
  const float* Wo = (const float*)d_in[4];
  float* out = (float*)d_out;

  char* p = (char*)d_ws;
  auto alloc = [&](size_t bytes) {
    void* r = (void*)p;
    p += (bytes + 255) & ~(size_t)255;
    return r;
  };
  const size_t BS = (size_t)BATCH * SEQ;     // 16384
  const size_t BC = (size_t)BATCH * NCHUNK;  // 4096
  ushort_t* Hh = (ushort_t*)alloc(BS * 512 * 2);
  ushort_t* Hl = (ushort_t*)alloc(BS * 512 * 2);
  ushort_t* Hph = (ushort_t*)alloc(BC * 512 * 2);
  ushort_t* Hpl = (ushort_t*)alloc(BC * 512 * 2);
  ushort_t* Wtq_h = (ushort_t*)alloc(512 * 512 * 2);
  ushort_t* Wtq_l = (ushort_t*)alloc(512 * 512 * 2);
  ushort_t* Wtkv_h = (ushort_t*)alloc(1024 * 512 * 2);
  ushort_t* Wtkv_l = (ushort_t*)alloc(1024 * 512 * 2);
  ushort_t* Qh = (ushort_t*)alloc(BS * 512 * 2);
  ushort_t* Ql = (ushort_t*)alloc(BS * 512 * 2);
  ushort_t* Pkvh = (ushort_t*)alloc(BC * 1024 * 2);
  ushort_t* Pkvl = (ushort_t*)alloc(BC * 1024 * 2);
  ushort_t* VWth = (ushort_t*)alloc((size_t)BATCH * 512 * 64 * 2);
  ushort_t* VWtl = (ushort_t*)alloc((size_t)BATCH * 512 * 64 * 2);
  uint* route = (uint*)alloc(BC * 4);
  uint* route2 = (uint*)alloc((size_t)BATCH * NSEL * 4);
  int* cand = (int*)alloc(BATCH * NSEL * 4);

  // 1. prep: pool/split H (+route zero) and weight transpose/split
  prep_kernel<<<2240, 256, 0, stream>>>(H, Wq, Wk, Wv, Hh, Hl, Hph, Hpl,
                                        Wtq_h, Wtq_l, Wtkv_h, Wtkv_l, route);
  // 2. merged projections (Q + KV), single-buffer + XCD swizzle
  proj_kernel<<<768, 256, 0, stream>>>(Hh, Hl, Hph, Hpl, Wtq_h, Wtq_l,
                                       Wtkv_h, Wtkv_l, Qh, Ql, Pkvh, Pkvl);
  // 3. routing: bf16 screen -> bitonic top-32 -> exact rescore
  route_screen<<<512, 256, 0, stream>>>(Qh, Pkvh, route);
  topk_sel<<<BATCH, 256, 0, stream>>>(route, cand, route2);
  rescore_kernel<<<dim3(32, 8, 4), 256, 0, stream>>>(Qh, Ql, Pkvh, Pkvl, cand,
                                                     route2);
  // 4. VW = V_sel @ Wo (top-8 inline), then fused softmax + (P @ VW) -> out
  vw_kernel<<<dim3(8, BATCH), 256, 0, stream>>>(Pkvh, Pkvl, Wo, route2, cand,
                                                VWth, VWtl);
  attn_out_kernel<<<dim3(64, BATCH), 256, 0, stream>>>(
      Qh, Pkvh, Pkvl, route2, cand, VWth, VWtl, out);
  (void)in_sizes; (void)n_in; (void)out_size; (void)ws_size;
}

// Round 6
// 234.305 us; speedup vs baseline: 4.4954x; 1.0217x over previous
//
#include <hip/hip_runtime.h>

#define SEQ 4096
#define BATCH 4
#define EMB 512
#define NHEAD 8
#define HDIM 64
#define NCHUNK 1024
#define TOPK 8
#define NSEL 32
#define SCALING 0.125f

typedef unsigned int uint;
typedef unsigned short ushort_t;
typedef __attribute__((ext_vector_type(8))) short short8;
typedef __attribute__((ext_vector_type(4))) float f32x4;
typedef __attribute__((ext_vector_type(4))) unsigned short us4;
typedef __attribute__((ext_vector_type(8))) unsigned short us8;

// ---- bf16 split helpers (x ~= hi + lo, each bf16; RNE rounding) -----------
__device__ __forceinline__ ushort_t bf16_rn(float x) {
  uint b = __float_as_uint(x);
  return (ushort_t)((b + 0x7FFFu + ((b >> 16) & 1u)) >> 16);
}
__device__ __forceinline__ float bf16_f(ushort_t u) {
  return __uint_as_float(((uint)u) << 16);
}

// ---- async global->LDS, 16B per lane (dst = wave base + lane*16) ----------
__device__ __forceinline__ void load_lds16(const void* g, void* l) {
  __builtin_amdgcn_global_load_lds(
      (const __attribute__((address_space(1))) unsigned int*)g,
      (__attribute__((address_space(3))) unsigned int*)l, 16, 0, 0);
}

__device__ __forceinline__ f32x4 mfma16(short8 a, short8 b, f32x4 c) {
  return __builtin_amdgcn_mfma_f32_16x16x32_bf16(a, b, c, 0, 0, 0);
}

__device__ __forceinline__ uint float_key(float f) {
  uint bits = __float_as_uint(f);
  return (bits & 0x80000000u) ? ~bits : (bits | 0x80000000u);
}

// ---- deterministic top-8 of the 32 rescored candidates (one wave) ---------
__device__ __forceinline__ void top8_inline(const uint* __restrict__ route2,
                                            const int* __restrict__ cand,
                                            int b, int lane,
                                            int* __restrict__ tops) {
  uint key = (lane < NSEL) ? route2[b * NSEL + lane] : 0u;
  const int myc = (lane < NSEL) ? cand[b * NSEL + lane] : 0;
  for (int it = 0; it < TOPK; ++it) {
    unsigned long long kk = ((unsigned long long)key << 32) | (uint)(63 - lane);
#pragma unroll
    for (int o = 32; o > 0; o >>= 1) {
      unsigned long long ot = __shfl_xor(kk, o, 64);
      kk = (ot > kk) ? ot : kk;
    }
    int widx = 63 - (int)(kk & 0xffffffffu);
    if (lane == widx) {
      tops[it] = myc;
      key = 0u;
    }
  }
}

// ---------------------------------------------------------------------------
// Prep (merged): blocks 0..2047 = pool+split of H (+ route zero);
// blocks 2048..2239 = weight transpose+split (Wq, Wk, Wv).
// ---------------------------------------------------------------------------
__global__ __launch_bounds__(256) void prep_kernel(
    const float* __restrict__ H, const float* __restrict__ Wq,
    const float* __restrict__ Wk, const float* __restrict__ Wv,
    ushort_t* __restrict__ Hh, ushort_t* __restrict__ Hl,
    ushort_t* __restrict__ Hph, ushort_t* __restrict__ Hpl,
    ushort_t* __restrict__ Wtq_h, ushort_t* __restrict__ Wtq_l,
    ushort_t* __restrict__ Wtkv_h, ushort_t* __restrict__ Wtkv_l,
    uint* __restrict__ route) {
  __shared__ float t[64][65];
  const int tid = threadIdx.x;
  if (blockIdx.x < 2048) {
    const int idx = blockIdx.x * 256 + tid;  // < 4*1024*128
    if (idx < BATCH * NCHUNK) route[idx] = 0;
    const int e4 = (idx & 127) << 2;
    const int c = (idx >> 7) & 1023;
    const int b = idx >> 17;
    const size_t rbase = ((size_t)(b * SEQ + c * 4)) * 512 + e4;
    float4 s = make_float4(0.f, 0.f, 0.f, 0.f);
#pragma unroll
    for (int j = 0; j < 4; ++j) {
      float4 v = *(const float4*)&H[rbase + (size_t)j * 512];
      s.x += v.x; s.y += v.y; s.z += v.z; s.w += v.w;
      us4 h, l;
      float a[4] = {v.x, v.y, v.z, v.w};
#pragma unroll
      for (int q = 0; q < 4; ++q) {
        ushort_t hb = bf16_rn(a[q]);
        h[q] = hb;
        l[q] = bf16_rn(a[q] - bf16_f(hb));
      }
      *(us4*)&Hh[rbase + (size_t)j * 512] = h;
      *(us4*)&Hl[rbase + (size_t)j * 512] = l;
    }
    float a[4] = {s.x * 0.25f, s.y * 0.25f, s.z * 0.25f, s.w * 0.25f};
    us4 h, l;
#pragma unroll
    for (int q = 0; q < 4; ++q) {
      ushort_t hb = bf16_rn(a[q]);
      h[q] = hb;
      l[q] = bf16_rn(a[q] - bf16_f(hb));
    }
    size_t po = ((size_t)(b * NCHUNK + c)) * 512 + e4;
    *(us4*)&Hph[po] = h;
    *(us4*)&Hpl[po] = l;
  } else {
    const int bid2 = blockIdx.x - 2048;  // 0..191
    const int z = bid2 >> 6;             // matrix
    const int xy = bid2 & 63;
    const int k0 = (xy & 7) * 64, n0 = (xy >> 3) * 64;
    const float* src = (z == 0) ? Wq : (z == 1) ? Wk : Wv;
    ushort_t* dh = (z == 0) ? Wtq_h : Wtkv_h;
    ushort_t* dl = (z == 0) ? Wtq_l : Wtkv_l;
    const size_t obase = (z == 2) ? (size_t)512 * 512 : 0;  // Wv rows 512+
#pragma unroll
    for (int i = 0; i < 4; ++i) {
      int row = (tid >> 4) + i * 16, col = (tid & 15) * 4;
      float4 v = *(const float4*)&src[(size_t)(k0 + row) * 512 + n0 + col];
      t[row][col + 0] = v.x; t[row][col + 1] = v.y;
      t[row][col + 2] = v.z; t[row][col + 3] = v.w;
    }
    __syncthreads();
#pragma unroll
    for (int i = 0; i < 4; ++i) {
      int nrow = (tid >> 4) + i * 16, kcol = (tid & 15) * 4;
      us4 h, l;
#pragma unroll
      for (int j = 0; j < 4; ++j) {
        float v = t[kcol + j][nrow];
        ushort_t hb = bf16_rn(v);
        h[j] = hb;
        l[j] = bf16_rn(v - bf16_f(hb));
      }
      size_t o = obase + (size_t)(n0 + nrow) * 512 + k0 + kcol;
      *(us4*)&dh[o] = h;
      *(us4*)&dl[o] = l;
    }
  }
}

// ---------------------------------------------------------------------------
// Merged projection GEMMs (Q full-seq + K|V pooled), split-bf16 3 products.
// Tile 64x128, BK=32, single-buffer LDS (24 KB -> 6 blocks/CU; grid 1536 =
// exactly 6/CU, fully resident). global_load_lds(16B), XOR swizzle.
// XCD remap: the col-blocks of one A row-panel share blockIdx%8.
// Blocks 0..1023: Q (16384x512); 1024..1535: KV (4096x1024).
// ---------------------------------------------------------------------------
__global__ __launch_bounds__(256) void proj_kernel(
    const ushort_t* __restrict__ Hh, const ushort_t* __restrict__ Hl,
    const ushort_t* __restrict__ Hph, const ushort_t* __restrict__ Hpl,
    const ushort_t* __restrict__ Wtq_h, const ushort_t* __restrict__ Wtq_l,
    const ushort_t* __restrict__ Wtkv_h, const ushort_t* __restrict__ Wtkv_l,
    ushort_t* __restrict__ Qh, ushort_t* __restrict__ Ql,
    ushort_t* __restrict__ Pkvh, ushort_t* __restrict__ Pkvl) {
  __shared__ ushort_t ldsA[2][2048];  // [h/l][64*32]   8 KB
  __shared__ ushort_t ldsB[2][4096];  // [h/l][128*32] 16 KB
  const int bid = blockIdx.x;
  const ushort_t *A0, *A1, *B0, *B1;
  ushort_t *Ch, *Cl;
  int ldc, row0, col0;
  if (bid < 1024) {  // Q: 256 row-panels(64) x 4 col-blocks(128)
    int xcd = bid & 7, idx = bid >> 3;       // idx 0..127
    int c = idx & 3, rr = idx >> 2;          // rr 0..31
    row0 = (rr * 8 + xcd) * 64; col0 = c * 128;
    A0 = Hh; A1 = Hl; B0 = Wtq_h; B1 = Wtq_l; Ch = Qh; Cl = Ql; ldc = 512;
  } else {  // KV: 64 row-panels(64) x 8 col-blocks(128)
    int b2 = bid - 1024;                     // 0..511
    int xcd = b2 & 7, idx = b2 >> 3;         // 0..63
    int c = idx & 7, rr = idx >> 3;          // rr 0..7
    row0 = (rr * 8 + xcd) * 64; col0 = c * 128;
    A0 = Hph; A1 = Hpl; B0 = Wtkv_h; B1 = Wtkv_l; Ch = Pkvh; Cl = Pkvl;
    ldc = 1024;
  }
  A0 += (size_t)row0 * 512; A1 += (size_t)row0 * 512;
  B0 += (size_t)col0 * 512; B1 += (size_t)col0 * 512;
  const int tid = threadIdx.x, lane = tid & 63, wv = tid >> 6;
  const int l15 = lane & 15, g = lane >> 4;
  const int wm = wv >> 1, wn = wv & 1;  // 32-row half, 64-col half
  f32x4 acc[2][4];
#pragma unroll
  for (int m = 0; m < 2; ++m)
#pragma unroll
    for (int n = 0; n < 4; ++n) acc[m][n] = (f32x4){0.f, 0.f, 0.f, 0.f};

  auto stage = [&](int t) {
    {  // A: 64x32 hi/lo, 256 16B-loads each
      int si = wv * 64 + lane;
      int row = si >> 2;
      int kb = ((si & 3) << 4) ^ (((row >> 1) & 3) << 4);
      size_t goff = (size_t)row * 512 + t * 32 + (kb >> 1);
      load_lds16(A0 + goff, &ldsA[0][si * 8]);
      load_lds16(A1 + goff, &ldsA[1][si * 8]);
    }
#pragma unroll
    for (int j = 0; j < 2; ++j) {  // B: 128x32 hi/lo, 512 16B-loads each
      int si = j * 256 + wv * 64 + lane;
      int row = si >> 2;
      int kb = ((si & 3) << 4) ^ (((row >> 1) & 3) << 4);
      size_t goff = (size_t)row * 512 + t * 32 + (kb >> 1);
      load_lds16(B0 + goff, &ldsB[0][si * 8]);
      load_lds16(B1 + goff, &ldsB[1][si * 8]);
    }
  };

  stage(0);
  for (int t = 0; t < 16; ++t) {
    __syncthreads();  // drains vmcnt -> staged tile visible
    short8 ah[2], al[2], bh[4], bl[4];
#pragma unroll
    for (int m = 0; m < 2; ++m) {
      int r = wm * 32 + m * 16 + l15;
      int kb = (g << 4) ^ (((r >> 1) & 3) << 4);
      ah[m] = *(const short8*)&ldsA[0][r * 32 + (kb >> 1)];
      al[m] = *(const short8*)&ldsA[1][r * 32 + (kb >> 1)];
    }
#pragma unroll
    for (int n = 0; n < 4; ++n) {
      int r = wn * 64 + n * 16 + l15;
      int kb = (g << 4) ^ (((r >> 1) & 3) << 4);
      bh[n] = *(const short8*)&ldsB[0][r * 32 + (kb >> 1)];
      bl[n] = *(const short8*)&ldsB[1][r * 32 + (kb >> 1)];
    }
#pragma unroll
    for (int m = 0; m < 2; ++m)
#pragma unroll
      for (int n = 0; n < 4; ++n) {
        acc[m][n] = mfma16(ah[m], bh[n], acc[m][n]);
        acc[m][n] = mfma16(ah[m], bl[n], acc[m][n]);
        acc[m][n] = mfma16(al[m], bh[n], acc[m][n]);
      }
    __syncthreads();  // all reads done before overwrite
    if (t < 15) stage(t + 1);
  }
#pragma unroll
  for (int m = 0; m < 2; ++m)
#pragma unroll
    for (int n = 0; n < 4; ++n)
#pragma unroll
      for (int q = 0; q < 4; ++q) {
        int row = row0 + wm * 32 + m * 16 + g * 4 + q;
        int col = col0 + wn * 64 + n * 16 + l15;
        float v = acc[m][n][q];
        size_t o = (size_t)row * ldc + col;
        ushort_t hb = bf16_rn(v);
        Ch[o] = hb;
        Cl[o] = bf16_rn(v - bf16_f(hb));
      }
}

// ---------------------------------------------------------------------------
// Screen: per (b,h,s-quarter): S = Qh(1024x64) @ Pkh^T (bf16, 1 product),
// fused col-max -> atomicMax(route). 1024 blocks (4/CU). XCD remap: the 8
// c0-blocks of one (b,h,sq) group share blockIdx%8 (Q slice L2-resident).
// ---------------------------------------------------------------------------
__device__ __forceinline__ void stage128x64(const ushort_t* src, int stride,
                                            ushort_t* dst, int wv, int lane) {
#pragma unroll
  for (int j = 0; j < 4; ++j) {
    int si = j * 256 + wv * 64 + lane;
    int row = si >> 3;
    int kb = ((si & 7) << 4) ^ ((row & 7) << 4);
    load_lds16(src + (size_t)row * stride + (kb >> 1),
               dst + (size_t)(j * 256 + wv * 64) * 8);
  }
}

__global__ __launch_bounds__(256) void route_screen(
    const ushort_t* __restrict__ Qh, const ushort_t* __restrict__ Pkh,
    uint* __restrict__ route) {
  __shared__ ushort_t Alds[128 * 64];  // 16 KB
  __shared__ ushort_t Blds[128 * 64];  // 16 KB
  __shared__ float red[2][128];
  const int tid = threadIdx.x, lane = tid & 63, wv = tid >> 6;
  const int l15 = lane & 15, g = lane >> 4;
  const int wm = wv >> 1, wc = wv & 1;
  const int bid = blockIdx.x;  // 1024 blocks
  const int gl = bid & 7, c0i = (bid >> 3) & 7, gh = bid >> 6;  // gh 0..15
  const int grp = gh * 8 + gl;  // 0..127 = b*32 + h*4 + sq
  const int b = grp >> 5, h = (grp >> 2) & 7, sq = grp & 3;
  const int c0 = c0i * 128;
  const int s0 = sq * 1024;
  const ushort_t* Qhb = Qh + ((size_t)b * SEQ) * 512 + h * 64;
  const ushort_t* Pkhb = Pkh + ((size_t)(b * NCHUNK + c0)) * 1024 + h * 64;

  stage128x64(Pkhb, 1024, &Blds[0], wv, lane);
  stage128x64(Qhb + (size_t)s0 * 512, 512, &Alds[0], wv, lane);
  __syncthreads();  // drains B + A(0)
  short8 bh[2][4];
#pragma unroll
  for (int kk = 0; kk < 2; ++kk)
#pragma unroll
    for (int n = 0; n < 4; ++n) {
      int r = wc * 64 + n * 16 + l15;
      int kb = (kk * 64 + (g << 4)) ^ ((r & 7) << 4);
      bh[kk][n] = *(const short8*)&Blds[r * 64 + (kb >> 1)];
    }

  float rmax[4] = {-1e30f, -1e30f, -1e30f, -1e30f};
  for (int it = 0; it < 8; ++it) {
    f32x4 acc[4][4];
#pragma unroll
    for (int m = 0; m < 4; ++m)
#pragma unroll
      for (int n = 0; n < 4; ++n) acc[m][n] = (f32x4){0.f, 0.f, 0.f, 0.f};
#pragma unroll
    for (int kk = 0; kk < 2; ++kk) {
      short8 ah[4];
#pragma unroll
      for (int m = 0; m < 4; ++m) {
        int r = wm * 64 + m * 16 + l15;
        int kb = (kk * 64 + (g << 4)) ^ ((r & 7) << 4);
        ah[m] = *(const short8*)&Alds[r * 64 + (kb >> 1)];
      }
#pragma unroll
      for (int m = 0; m < 4; ++m)
#pragma unroll
        for (int n = 0; n < 4; ++n)
          acc[m][n] = mfma16(ah[m], bh[kk][n], acc[m][n]);
    }
#pragma unroll
    for (int n = 0; n < 4; ++n)
#pragma unroll
      for (int m = 0; m < 4; ++m)
        rmax[n] = fmaxf(rmax[n],
                        fmaxf(fmaxf(acc[m][n][0], acc[m][n][1]),
                              fmaxf(acc[m][n][2], acc[m][n][3])));
    __syncthreads();  // readers done
    if (it < 7) {
      size_t so = (size_t)(s0 + (it + 1) * 128) * 512;
      stage128x64(Qhb + so, 512, &Alds[0], wv, lane);
    }
    __syncthreads();  // drain vmcnt -> next tile visible
  }
#pragma unroll
  for (int n = 0; n < 4; ++n) {
    float v = rmax[n];
    v = fmaxf(v, __shfl_xor(v, 16, 64));
    v = fmaxf(v, __shfl_xor(v, 32, 64));
    if (g == 0) red[wm][wc * 64 + n * 16 + l15] = v;
  }
  __syncthreads();
  if (tid < 128) {
    float v = fmaxf(red[0][tid], red[1][tid]);
    atomicMax(&route[b * NCHUNK + c0 + tid], float_key(v));
  }
}

// ---------------------------------------------------------------------------
// Top-NSEL via bitonic sort of 1024 keys; zeroes route2 for the rescore.
// ---------------------------------------------------------------------------
__global__ __launch_bounds__(256) void topk_sel(const uint* __restrict__ route,
                                                int* __restrict__ cand,
                                                uint* __restrict__ route2) {
  const int b = blockIdx.x, tid = threadIdx.x;
  __shared__ unsigned long long keys[NCHUNK];
#pragma unroll
  for (int i = 0; i < 4; ++i) {
    int idx = tid + i * 256;
    keys[idx] = ((unsigned long long)route[b * NCHUNK + idx] << 32) |
                (uint)(NCHUNK - 1 - idx);  // tie -> lower index first
  }
  if (tid < NSEL) route2[b * NSEL + tid] = 0;
  __syncthreads();
  for (int k = 2; k <= NCHUNK; k <<= 1) {
    for (int j = k >> 1; j > 0; j >>= 1) {
#pragma unroll
      for (int ii = 0; ii < 4; ++ii) {
        int i = tid + ii * 256;
        int p = i ^ j;
        if (p > i) {
          bool desc = ((i & k) == 0);
          unsigned long long a = keys[i], c = keys[p];
          bool sw = desc ? (a < c) : (a > c);
          if (sw) { keys[i] = c; keys[p] = a; }
        }
      }
      __syncthreads();
    }
  }
  if (tid < NSEL)
    cand[b * NSEL + tid] = NCHUNK - 1 - (int)(keys[tid] & 0xffffffffu);
}

// ---------------------------------------------------------------------------
// Exact rescore of the 32 candidates: split-bf16 3 products, B gathered
// directly from Pkv via cand. Fused col-max -> atomicMax(route2).
// ---------------------------------------------------------------------------
__global__ __launch_bounds__(256) void rescore_kernel(
    const ushort_t* __restrict__ Qh, const ushort_t* __restrict__ Ql,
    const ushort_t* __restrict__ Pkvh, const ushort_t* __restrict__ Pkvl,
    const int* __restrict__ cand, uint* __restrict__ route2) {
  __shared__ ushort_t Ah[128 * 64], Al[128 * 64];
  __shared__ ushort_t Bh[NSEL * 64], Bl[NSEL * 64];
  __shared__ float red[4][NSEL];
  const int tid = threadIdx.x, lane = tid & 63, wv = tid >> 6;
  const int l15 = lane & 15, g = lane >> 4;
  const int st = blockIdx.x, h = blockIdx.y, b = blockIdx.z;
  const int s0 = st * 128;
  {
    int row = tid >> 3;
    int kb = ((tid & 7) << 4) ^ ((row & 7) << 4);
    int c = cand[b * NSEL + row];
    size_t src = ((size_t)(b * NCHUNK + c)) * 1024 + h * 64 + (kb >> 1);
    load_lds16(Pkvh + src, &Bh[(size_t)(wv * 64) * 8]);
    load_lds16(Pkvl + src, &Bl[(size_t)(wv * 64) * 8]);
  }
  const ushort_t* Qhb = Qh + ((size_t)(b * SEQ + s0)) * 512 + h * 64;
  const ushort_t* Qlb = Ql + ((size_t)(b * SEQ + s0)) * 512 + h * 64;
  stage128x64(Qhb, 512, Ah, wv, lane);
  stage128x64(Qlb, 512, Al, wv, lane);
  __syncthreads();

  f32x4 acc[2][2];
#pragma unroll
  for (int m = 0; m < 2; ++m)
#pragma unroll
    for (int n = 0; n < 2; ++n) acc[m][n] = (f32x4){0.f, 0.f, 0.f, 0.f};
#pragma unroll
  for (int kk = 0; kk < 2; ++kk) {
    short8 ah[2], al[2], bh[2], bl[2];
#pragma unroll
    for (int m = 0; m < 2; ++m) {
      int r = wv * 32 + m * 16 + l15;
      int kb = (kk * 64 + (g << 4)) ^ ((r & 7) << 4);
      ah[m] = *(const short8*)&Ah[r * 64 + (kb >> 1)];
      al[m] = *(const short8*)&Al[r * 64 + (kb >> 1)];
    }
#pragma unroll
    for (int n = 0; n < 2; ++n) {
      int r = n * 16 + l15;
      int kb = (kk * 64 + (g << 4)) ^ ((r & 7) << 4);
      bh[n] = *(const short8*)&Bh[r * 64 + (kb >> 1)];
      bl[n] = *(const short8*)&Bl[r * 64 + (kb >> 1)];
    }
#pragma unroll
    for (int m = 0; m < 2; ++m)
#pragma unroll
      for (int n = 0; n < 2; ++n) {
        acc[m][n] = mfma16(ah[m], bh[n], acc[m][n]);
        acc[m][n] = mfma16(ah[m], bl[n], acc[m][n]);
        acc[m][n] = mfma16(al[m], bh[n], acc[m][n]);
      }
  }
#pragma unroll
  for (int n = 0; n < 2; ++n) {
    float v = -1e30f;
#pragma unroll
    for (int m = 0; m < 2; ++m)
      v = fmaxf(v, fmaxf(fmaxf(acc[m][n][0], acc[m][n][1]),
                         fmaxf(acc[m][n][2], acc[m][n][3])));
    v = fmaxf(v, __shfl_xor(v, 16, 64));
    v = fmaxf(v, __shfl_xor(v, 32, 64));
    if (g == 0) red[wv][n * 16 + l15] = v;
  }
  __syncthreads();
  if (tid < NSEL) {
    float v = fmaxf(fmaxf(red[0][tid], red[1][tid]),
                    fmaxf(red[2][tid], red[3][tid]));
    atomicMax(&route2[b * NSEL + tid], float_key(v));
  }
}

// ---------------------------------------------------------------------------
// VW[b][hj][e] = sum_d V_sel[b,j,h,d]*Wo[h*64+d][e]; transposed split output.
// Top-8 recomputed inline (deterministic) -> no topidx dependency kernel.
// ---------------------------------------------------------------------------
__global__ __launch_bounds__(256) void vw_kernel(
    const ushort_t* __restrict__ Pkvh, const ushort_t* __restrict__ Pkvl,
    const float* __restrict__ Wo, const uint* __restrict__ route2,
    const int* __restrict__ cand, ushort_t* __restrict__ VWth,
    ushort_t* __restrict__ VWtl) {
  __shared__ float Vs[8][512];
  __shared__ int tops[TOPK];
  const int tid = threadIdx.x, et = blockIdx.x, b = blockIdx.y;
  if (tid < 64) top8_inline(route2, cand, b, tid, tops);
  __syncthreads();
#pragma unroll
  for (int i = 0; i < 16; ++i) {
    int idx = tid + i * 256;  // < 4096
    int j = idx >> 9, d = idx & 511;
    int c = tops[j];
    size_t src = ((size_t)(b * NCHUNK + c)) * 1024 + 512 + d;
    Vs[j][d] = bf16_f(Pkvh[src]) + bf16_f(Pkvl[src]);
  }
  __syncthreads();
  const int e = et * 64 + (tid & 63), qr = tid >> 6;
  ushort_t hbuf[16], lbuf[16];
#pragma unroll
  for (int i = 0; i < 16; ++i) {
    int hj = qr * 16 + i, h = hj >> 3, j = hj & 7;
    float dot = 0.f;
#pragma unroll
    for (int d = 0; d < 64; ++d)
      dot += Vs[j][h * 64 + d] * Wo[(size_t)(h * 64 + d) * 512 + e];
    ushort_t hb = bf16_rn(dot);
    hbuf[i] = hb;
    lbuf[i] = bf16_rn(dot - bf16_f(hb));
  }
  size_t o = ((size_t)(b * 512 + e)) * 64 + qr * 16;
  *(us8*)&VWth[o] = *(us8*)&hbuf[0];
  *(us8*)&VWth[o + 8] = *(us8*)&hbuf[8];
  *(us8*)&VWtl[o] = *(us8*)&lbuf[0];
  *(us8*)&VWtl[o + 8] = *(us8*)&lbuf[8];
}

// ---------------------------------------------------------------------------
// Fused attention epilogue: top-8 inline, softmax weights P (Qh-only scores,
// split-bf16 into swizzled LDS), then out = P @ VW via MFMA (3 products).
// ---------------------------------------------------------------------------
__global__ __launch_bounds__(256) void attn_out_kernel(
    const ushort_t* __restrict__ Qh, const ushort_t* __restrict__ Pkvh,
    const ushort_t* __restrict__ Pkvl, const uint* __restrict__ route2,
    const int* __restrict__ cand, const ushort_t* __restrict__ VWth,
    const ushort_t* __restrict__ VWtl, float* __restrict__ out) {
  __shared__ float Ksel[8 * 516];  // [h*516 + j*64 + d]
  __shared__ ushort_t Pho[64 * 64], Plo[64 * 64];  // swizzled
  __shared__ int tops[TOPK];
  const int tid = threadIdx.x, lane = tid & 63, wv = tid >> 6;
  const int l15 = lane & 15, g = lane >> 4;
  const int st = blockIdx.x, b = blockIdx.y;
  const int s0 = st * 64;
  if (tid < 64) top8_inline(route2, cand, b, tid, tops);
  __syncthreads();
  // ---- load K_sel (hi+lo -> f32)
  {
    int j = tid >> 5, h = (tid >> 2) & 7, dg = tid & 3;
    int c = tops[j];
    size_t base = ((size_t)(b * NCHUNK + c)) * 1024 + h * 64 + dg * 16;
    us8 h0 = *(const us8*)&Pkvh[base], h1 = *(const us8*)&Pkvh[base + 8];
    us8 l0 = *(const us8*)&Pkvl[base], l1 = *(const us8*)&Pkvl[base + 8];
#pragma unroll
    for (int ii = 0; ii < 8; ++ii) {
      Ksel[h * 516 + j * 64 + dg * 16 + ii] = bf16_f(h0[ii]) + bf16_f(l0[ii]);
      Ksel[h * 516 + j * 64 + dg * 16 + 8 + ii] =
          bf16_f(h1[ii]) + bf16_f(l1[ii]);
    }
  }
  __syncthreads();
  // ---- phase 1: P rows s0..s0+63 (thread = (row, 2-head pair)); Qh only
  {
    const int r = tid >> 2, hp = tid & 3;
    const size_t qbase = ((size_t)(b * SEQ + s0 + r)) * 512;
#pragma unroll
    for (int hh = 0; hh < 2; ++hh) {
      const int h = hp * 2 + hh;
      float qf[64];
#pragma unroll
      for (int i = 0; i < 8; ++i) {
        us8 vh = *(const us8*)&Qh[qbase + h * 64 + i * 8];
#pragma unroll
        for (int k2 = 0; k2 < 8; ++k2) qf[i * 8 + k2] = bf16_f(vh[k2]);
      }
      float sc[TOPK], m = -1e30f;
#pragma unroll
      for (int j = 0; j < TOPK; ++j) {
        float dot = 0.f;
#pragma unroll
        for (int d4 = 0; d4 < 16; ++d4) {
          float4 kv = *(const float4*)&Ksel[h * 516 + j * 64 + d4 * 4];
          dot += qf[d4 * 4 + 0] * kv.x + qf[d4 * 4 + 1] * kv.y +
                 qf[d4 * 4 + 2] * kv.z + qf[d4 * 4 + 3] * kv.w;
        }
        sc[j] = dot * SCALING;
        m = fmaxf(m, sc[j]);
      }
      float se = 0.f, w8[TOPK];
#pragma unroll
      for (int j = 0; j < TOPK; ++j) {
        w8[j] = __expf(sc[j] - m);
        se += w8[j];
      }
      const float inv = 1.f / se;
      us8 ph8, pl8;
#pragma unroll
      for (int j = 0; j < TOPK; ++j) {
        float pv = w8[j] * inv;
        ushort_t hb = bf16_rn(pv);
        ph8[j] = hb;
        pl8[j] = bf16_rn(pv - bf16_f(hb));
      }
      int boff = (r * 128 + h * 16) ^ ((r & 7) << 4);
      *(us8*)((char*)Pho + boff) = ph8;
      *(us8*)((char*)Plo + boff) = pl8;
    }
  }
  __syncthreads();
  // ---- phase 2: out(64 x 512) = P(64x64) @ VW(64x512); wave -> 128 cols
  short8 pa[4][2], pb[4][2];
#pragma unroll
  for (int m = 0; m < 4; ++m) {
    int r = m * 16 + l15;
#pragma unroll
    for (int kk = 0; kk < 2; ++kk) {
      int boff = (r * 128 + kk * 64 + g * 16) ^ ((r & 7) << 4);
      pa[m][kk] = *(const short8*)((const char*)Pho + boff);
      pb[m][kk] = *(const short8*)((const char*)Plo + boff);
    }
  }
#pragma unroll
  for (int half = 0; half < 2; ++half) {
    const int colbase = wv * 128 + half * 64;
    short8 bh[4][2], bl[4][2];
#pragma unroll
    for (int n = 0; n < 4; ++n) {
      int e = colbase + n * 16 + l15;
      size_t vb = ((size_t)(b * 512 + e)) * 64;
#pragma unroll
      for (int kk = 0; kk < 2; ++kk) {
        bh[n][kk] = *(const short8*)&VWth[vb + kk * 32 + g * 8];
        bl[n][kk] = *(const short8*)&VWtl[vb + kk * 32 + g * 8];
      }
    }
    f32x4 acc[4][4];
#pragma unroll
    for (int m = 0; m < 4; ++m)
#pragma unroll
      for (int n = 0; n < 4; ++n) acc[m][n] = (f32x4){0.f, 0.f, 0.f, 0.f};
#pragma unroll
    for (int kk = 0; kk < 2; ++kk)
#pragma unroll
      for (int m = 0; m < 4; ++m)
#pragma unroll
        for (int n = 0; n < 4; ++n) {
          acc[m][n] = mfma16(pa[m][kk], bh[n][kk], acc[m][n]);
          acc[m][n] = mfma16(pa[m][kk], bl[n][kk], acc[m][n]);
          acc[m][n] = mfma16(pb[m][kk], bh[n][kk], acc[m][n]);
        }
#pragma unroll
    for (int m = 0; m < 4; ++m)
#pragma unroll
      for (int n = 0; n < 4; ++n)
#pragma unroll
        for (int q = 0; q < 4; ++q) {
          int row = s0 + m * 16 + g * 4 + q;
          int col = colbase + n * 16 + l15;
          out[((size_t)(b * SEQ) + row) * 512 + col] = acc[m][n][q];
        }
  }
}

// ---------------------------------------------------------------------------
extern "C" void kernel_launch(void* const* d_in, const int* in_sizes, int n_in,
                              void* d_out, int out_size, void* d_ws, size_t ws_size,
                              hipStream_t stream) {
  const float* H = (const float*)d_in[0];
  const float* Wq = (const float*)d_in[1];
  const float* Wk = (const float*)d_in[2];
  const float* Wv = (const float*)d_in[3];
  const float* Wo = (const float*)d_in[4];
  float* out = (float*)d_out;

  char* p = (char*)d_ws;
  auto alloc = [&](size_t bytes) {
    void* r = (void*)p;
    p += (bytes + 255) & ~(size_t)255;
    return r;
  };
  const size_t BS = (size_t)BATCH * SEQ;     // 16384
  const size_t BC = (size_t)BATCH * NCHUNK;  // 4096
  ushort_t* Hh = (ushort_t*)alloc(BS * 512 * 2);
  ushort_t* Hl = (ushort_t*)alloc(BS * 512 * 2);
  ushort_t* Hph = (ushort_t*)alloc(BC * 512 * 2);
  ushort_t* Hpl = (ushort_t*)alloc(BC * 512 * 2);
  ushort_t* Wtq_h = (ushort_t*)alloc(512 * 512 * 2);
  ushort_t* Wtq_l = (ushort_t*)alloc(512 * 512 * 2);
  ushort_t* Wtkv_h = (ushort_t*)alloc(1024 * 512 * 2);
  ushort_t* Wtkv_l = (ushort_t*)alloc(1024 * 512 * 2);
  ushort_t* Qh = (ushort_t*)alloc(BS * 512 * 2);
  ushort_t* Ql = (ushort_t*)alloc(BS * 512 * 2);
  ushort_t* Pkvh = (ushort_t*)alloc(BC * 1024 * 2);
  ushort_t* Pkvl = (ushort_t*)alloc(BC * 1024 * 2);
  ushort_t* VWth = (ushort_t*)alloc((size_t)BATCH * 512 * 64 * 2);
  ushort_t* VWtl = (ushort_t*)alloc((size_t)BATCH * 512 * 64 * 2);
  uint* route = (uint*)alloc(BC * 4);
  uint* route2 = (uint*)alloc((size_t)BATCH * NSEL * 4);
  int* cand = (int*)alloc(BATCH * NSEL * 4);

  // 1. prep: pool/split H (+route zero) and weight transpose/split
  prep_kernel<<<2240, 256, 0, stream>>>(H, Wq, Wk, Wv, Hh, Hl, Hph, Hpl,
                                        Wtq_h, Wtq_l, Wtkv_h, Wtkv_l, route);
  // 2. merged projections (Q + KV), 64x128 tiles, 6 blocks/CU
  proj_kernel<<<1536, 256, 0, stream>>>(Hh, Hl, Hph, Hpl, Wtq_h, Wtq_l,
                                        Wtkv_h, Wtkv_l, Qh, Ql, Pkvh, Pkvl);
  // 3. routing: bf16 screen (4/CU) -> bitonic top-32 -> exact rescore
  route_screen<<<1024, 256, 0, stream>>>(Qh, Pkvh, route);
  topk_sel<<<BATCH, 256, 0, stream>>>(route, cand, route2);
  rescore_kernel<<<dim3(32, 8, 4), 256, 0, stream>>>(Qh, Ql, Pkvh, Pkvl, cand,
                                                     route2);
  // 4. VW = V_sel @ Wo (top-8 inline), then fused softmax + (P @ VW) -> out
  vw_kernel<<<dim3(8, BATCH), 256, 0, stream>>>(Pkvh, Pkvl, Wo, route2, cand,
                                                VWth, VWtl);
  attn_out_kernel<<<dim3(64, BATCH), 256, 0, stream>>>(
      Qh, Pkvh, Pkvl, route2, cand, VWth, VWtl, out);
  (void)in_sizes; (void)n_in; (void)out_size; (void)ws_size;
}